// Round 4
// baseline (12229.621 us; speedup 1.0000x reference)
//
#include <hip/hip_runtime.h>
#include <math.h>

#define B_   1024
#define T_   64
#define H_   512
#define V_   1024
#define GEN_ 100
#define FH   2048   // 4*H
#define KC   1536   // 3*H concatenated-K for bf16x2 compensated GEMM

// ---------------- workspace layout (bytes) ----------------
static constexpr size_t MB = 1024ull * 1024;
static constexpr size_t OFF_G    = 0;            // 2 * B*FH fp32 split-K partials (16 MB)
static constexpr size_t OFF_C    = 16 * MB;      // B*H fp32 (2 MB)
static constexpr size_t OFF_WIHT = 18 * MB;      // V*FH fp32 (8 MB)
static constexpr size_t OFF_ACAT = 26 * MB;      // B*KC bf16 (3 MB)   [h_hi | h_hi | h_lo]
static constexpr size_t OFF_BCAT = 29 * MB;      // FH*KC bf16 (6 MB)  [W_hi | W_lo | W_hi]
static constexpr size_t OFF_BSUM = 35 * MB;      // FH fp32
static constexpr size_t OFF_TOK  = 35 * MB + 8192;   // B int (4 KB)
static constexpr size_t OFF_BAR  = 35 * MB + 16384;  // grid-barrier counter

typedef __attribute__((ext_vector_type(8))) short short8v;
typedef __attribute__((ext_vector_type(4))) float f32x4;

__device__ __forceinline__ float sigf(float x) { return 1.0f / (1.0f + expf(-x)); }

__device__ __forceinline__ unsigned short f2bf(float f) {  // RNE fp32 -> bf16
    unsigned int u = __float_as_uint(f);
    return (unsigned short)((u + 0x7FFFu + ((u >> 16) & 1u)) >> 16);
}
__device__ __forceinline__ float bf2f(unsigned short b) {
    return __uint_as_float(((unsigned int)b) << 16);
}

// Agent-scope (device-coherent) access helpers: bypass stale per-XCD L2 without
// any whole-cache writeback/invalidate. All cross-block data goes through these;
// read-only weights keep normal cached loads and stay warm in L2 across steps.
#define ALOAD64(p)     __hip_atomic_load((const unsigned long long*)(p), __ATOMIC_RELAXED, __HIP_MEMORY_SCOPE_AGENT)
#define ALOADF(p)      __hip_atomic_load((const float*)(p), __ATOMIC_RELAXED, __HIP_MEMORY_SCOPE_AGENT)
#define ASTORE32(p, v) __hip_atomic_store((unsigned int*)(p), (v), __ATOMIC_RELAXED, __HIP_MEMORY_SCOPE_AGENT)
#define ASTOREF(p, v)  __hip_atomic_store((float*)(p), (v), __ATOMIC_RELAXED, __HIP_MEMORY_SCOPE_AGENT)

// manual grid barrier, FENCE-FREE: __syncthreads drains vmcnt (our agent-scope
// stores are then visible at the coherence point); arrival/spin are relaxed
// agent atomics. No buffer_wbl2 / buffer_inv -> L2 keeps weights hot.
__device__ __forceinline__ void gsync(unsigned* cnt, unsigned target) {
    asm volatile("" ::: "memory");
    __syncthreads();
    if (threadIdx.x == 0) {
        __hip_atomic_fetch_add(cnt, 1u, __ATOMIC_RELAXED, __HIP_MEMORY_SCOPE_AGENT);
        while (__hip_atomic_load(cnt, __ATOMIC_RELAXED, __HIP_MEMORY_SCOPE_AGENT) < target)
            __builtin_amdgcn_s_sleep(1);
    }
    __syncthreads();
    asm volatile("" ::: "memory");
}

// ---------------- setup kernels ----------------
__global__ __launch_bounds__(256) void k_init(const float* __restrict__ input,
                                              const float* __restrict__ Wh, const float* __restrict__ bh,
                                              const float* __restrict__ Wc, const float* __restrict__ bc,
                                              const float* __restrict__ bih, const float* __restrict__ bhh,
                                              float* __restrict__ cbuf, short* __restrict__ acat,
                                              float* __restrict__ bsum, unsigned* __restrict__ gbar) {
    int idx = blockIdx.x * 256 + threadIdx.x;  // over B*H
    int b = idx >> 9, j = idx & (H_ - 1);
    float x = input[b];
    float h0 = x * Wh[j] + bh[j];
    cbuf[idx] = x * Wc[j] + bc[j];
    unsigned short hi = f2bf(h0);
    unsigned short lo = f2bf(h0 - bf2f(hi));
    short* ar = acat + (size_t)b * KC;
    ar[j] = (short)hi; ar[512 + j] = (short)hi; ar[1024 + j] = (short)lo;
    if (idx < FH) bsum[idx] = bih[idx] + bhh[idx];
    if (idx == 0) *gbar = 0u;
}

__global__ __launch_bounds__(256) void k_tok0(const float* __restrict__ onehots, int* __restrict__ tok) {
    int idx = blockIdx.x * 256 + threadIdx.x;  // over B*V
    int b = idx >> 10, v = idx & (V_ - 1);
    if (onehots[(size_t)b * (T_ * V_) + v] > 0.5f) tok[b] = v;  // exact one-hot: single writer
}

__global__ __launch_bounds__(256) void k_transpose(const float* __restrict__ Wih, float* __restrict__ WihT) {
    int idx = blockIdx.x * 256 + threadIdx.x;  // over V*FH
    int v = idx >> 11, n = idx & (FH - 1);
    WihT[idx] = Wih[(size_t)n * V_ + v];
}

__global__ __launch_bounds__(256) void k_prep(const float* __restrict__ Whh, short* __restrict__ bcat) {
    int idx = blockIdx.x * 256 + threadIdx.x;  // over FH*H
    int n = idx >> 9, k = idx & (H_ - 1);
    float w = Whh[idx];
    unsigned short hi = f2bf(w);
    unsigned short lo = f2bf(w - bf2f(hi));
    short* br = bcat + (size_t)n * KC;
    br[k] = (short)hi; br[512 + k] = (short)lo; br[1024 + k] = (short)hi;
}

// ---------------- persistent kernel: whole T-loop ----------------
// 128 blocks x 256 threads (<= half of device capacity -> co-residency guaranteed
// -> spin barrier deadlock-free). Each block: GEMM slice (TWO m-tiles 128, one
// n-tile 128, one k-half 768); 128n x 768k W-slice in VGPRs (48 short8v = 192
// VGPR/lane, statically indexed via FULL unroll). Head job: 8 rows b0 = bj*8.
__global__ __launch_bounds__(256, 1) void k_main(const short* __restrict__ bcat,
                                                 short* __restrict__ acat,
                                                 float* __restrict__ gpart,
                                                 float* __restrict__ cbuf,
                                                 const float* __restrict__ WihT,
                                                 const float* __restrict__ bsum,
                                                 int* __restrict__ tok,
                                                 const float* __restrict__ W1, const float* __restrict__ b1,
                                                 const float* __restrict__ W2, const float* __restrict__ b2,
                                                 float* __restrict__ outbase,
                                                 unsigned* __restrict__ gbar) {
    const int tid = threadIdx.x;
    const int lane = tid & 63, w = tid >> 6;
    const int quad = lane >> 4, l15 = lane & 15;
    const int bj = blockIdx.x;  // [0,128)

    // GEMM role: z = bj>>6 (k-half), nt = (bj>>2)&15 (n-tile), mp = bj&3 (m-pair)
    const int z  = bj >> 6;
    const int n0 = ((bj >> 2) & 15) * 128;
    const int k0 = z * 768;
    const int m0a = (bj & 3) * 128;
    const int m0b = ((bj & 3) + 4) * 128;
    float* __restrict__ gout = gpart + (size_t)z * (B_ * FH);

    // head role: 8 rows
    const int b0 = bj * 8;

    __shared__ __align__(16) short As[2][2][8192];  // [buf][mtile] 64 KB, XOR-chunk-swizzled
    __shared__ float hs[8][512];        // 16 KB
    __shared__ float pps[2][8][104];    // 6.6 KB
    __shared__ float ps[8][104];        // 3.4 KB
    __shared__ float red[8][4];
    __shared__ int  redi[8][4];

    // ---- load W-slice into registers (once): wave w owns n-rows [w*32, w*32+32)
    short8v wreg[2][24];
    {
        const short* wb = bcat + (size_t)(n0 + w * 32 + l15) * KC + k0 + quad * 8;
#pragma unroll
        for (int j = 0; j < 2; ++j)
#pragma unroll
            for (int kk = 0; kk < 24; ++kk)
                wreg[j][kk] = *(const short8v*)(wb + (size_t)(j * 16) * KC + kk * 32);
    }

    // ---- A staging geometry: reg-staged (agent-coherent 8B loads -> ds_write_b64),
    // same XOR 16B-chunk swizzle as before: chunk cs lands at slot cs^(row&7).
    const int row8 = lane >> 3;          // 0..7
    const int q    = lane & 7;           // 16B-chunk index
    const short* awA = acat + (size_t)(m0a + w * 32 + row8) * KC + k0 + q * 8;
    const short* awB = acat + (size_t)(m0b + w * 32 + row8) * KC + k0 + q * 8;
    const int lwoff = w * 2048 + row8 * 64 + (q ^ row8) * 8;  // shorts, within As[buf][mt]

    int raA[8], rxA[8];
#pragma unroll
    for (int mi = 0; mi < 8; ++mi) { int rm = mi * 16 + l15; raA[mi] = rm * 8; rxA[mi] = rm & 7; }

    unsigned bar_target = 0;

#pragma unroll 1
    for (int t = 0; t < T_; ++t) {
        // ================= segment 1: gates GEMM (W in VGPRs, 2 m-tiles) =================
        f32x4 accA[8][2], accB[8][2];
#pragma unroll
        for (int mi = 0; mi < 8; ++mi) {
            accA[mi][0] = (f32x4){0.f, 0.f, 0.f, 0.f}; accA[mi][1] = (f32x4){0.f, 0.f, 0.f, 0.f};
            accB[mi][0] = (f32x4){0.f, 0.f, 0.f, 0.f}; accB[mi][1] = (f32x4){0.f, 0.f, 0.f, 0.f};
        }
        unsigned long long rA[8], rB[8];
        // prologue: load k-iter 0 to regs, write buf0
#pragma unroll
        for (int g = 0; g < 4; ++g)
#pragma unroll
            for (int h = 0; h < 2; ++h) {
                rA[g * 2 + h] = ALOAD64(awA + (size_t)g * 8 * KC + h * 4);
                rB[g * 2 + h] = ALOAD64(awB + (size_t)g * 8 * KC + h * 4);
            }
#pragma unroll
        for (int g = 0; g < 4; ++g)
#pragma unroll
            for (int h = 0; h < 2; ++h) {
                *(unsigned long long*)&As[0][0][lwoff + g * 512 + h * 4] = rA[g * 2 + h];
                *(unsigned long long*)&As[0][1][lwoff + g * 512 + h * 4] = rB[g * 2 + h];
            }
        __syncthreads();
#pragma unroll
        for (int it = 0; it < 12; ++it) {   // FULL unroll: wreg indices static (rule #20)
            if (it < 11) {  // issue next k-iter loads early; latency hidden under MFMA
#pragma unroll
                for (int g = 0; g < 4; ++g)
#pragma unroll
                    for (int h = 0; h < 2; ++h) {
                        rA[g * 2 + h] = ALOAD64(awA + (it + 1) * 64 + (size_t)g * 8 * KC + h * 4);
                        rB[g * 2 + h] = ALOAD64(awB + (it + 1) * 64 + (size_t)g * 8 * KC + h * 4);
                    }
            }
            const short* Ab0 = &As[it & 1][0][0];
            const short* Ab1 = &As[it & 1][1][0];
#pragma unroll
            for (int kh = 0; kh < 2; ++kh) {
                const int c = kh * 4 + quad;
                short8v av[8];
#pragma unroll
                for (int mi = 0; mi < 8; ++mi)
                    av[mi] = *(const short8v*)&Ab0[(raA[mi] + (c ^ rxA[mi])) * 8];
#pragma unroll
                for (int mi = 0; mi < 8; ++mi) {
                    accA[mi][0] = __builtin_amdgcn_mfma_f32_16x16x32_bf16(av[mi], wreg[0][it * 2 + kh], accA[mi][0], 0, 0, 0);
                    accA[mi][1] = __builtin_amdgcn_mfma_f32_16x16x32_bf16(av[mi], wreg[1][it * 2 + kh], accA[mi][1], 0, 0, 0);
                }
#pragma unroll
                for (int mi = 0; mi < 8; ++mi)
                    av[mi] = *(const short8v*)&Ab1[(raA[mi] + (c ^ rxA[mi])) * 8];
#pragma unroll
                for (int mi = 0; mi < 8; ++mi) {
                    accB[mi][0] = __builtin_amdgcn_mfma_f32_16x16x32_bf16(av[mi], wreg[0][it * 2 + kh], accB[mi][0], 0, 0, 0);
                    accB[mi][1] = __builtin_amdgcn_mfma_f32_16x16x32_bf16(av[mi], wreg[1][it * 2 + kh], accB[mi][1], 0, 0, 0);
                }
            }
            if (it < 11) {  // write next buffer (safe: last read of it^1 ended at prev barrier)
                const int nb = (it + 1) & 1;
#pragma unroll
                for (int g = 0; g < 4; ++g)
#pragma unroll
                    for (int h = 0; h < 2; ++h) {
                        *(unsigned long long*)&As[nb][0][lwoff + g * 512 + h * 4] = rA[g * 2 + h];
                        *(unsigned long long*)&As[nb][1][lwoff + g * 512 + h * 4] = rB[g * 2 + h];
                    }
            }
            __syncthreads();
        }
        // epilogue: C/D layout col(n)=lane&15, row(m)=quad*4+reg [m89]; agent-scope stores
#pragma unroll
        for (int mi = 0; mi < 8; ++mi) {
            const int ma = m0a + mi * 16 + quad * 4;
            const int mb = m0b + mi * 16 + quad * 4;
#pragma unroll
            for (int j = 0; j < 2; ++j) {
                const int n = n0 + w * 32 + j * 16 + l15;
                float* gpa = gout + (size_t)ma * FH + n;
                float* gpb = gout + (size_t)mb * FH + n;
#pragma unroll
                for (int r = 0; r < 4; ++r) {
                    ASTOREF(gpa + (size_t)r * FH, accA[mi][j][r]);
                    ASTOREF(gpb + (size_t)r * FH, accB[mi][j][r]);
                }
            }
        }
        bar_target += 128; gsync(gbar, bar_target);

        // ================= segment 2: cell + head + log_softmax + argmax (8 rows) =================
        {
            const float* __restrict__ g0 = gpart;
            const float* __restrict__ g1 = gpart + (size_t)B_ * FH;
            float* __restrict__ outt = outbase + (size_t)t * ((size_t)B_ * V_);

            // ---- phase 1: LSTM cell; pair-of-j per thread so acat writes pack to u32
#pragma unroll
            for (int ii = 0; ii < 8; ++ii) {
                const int idx = tid + ii * 256;        // 0..2047
                const int r = idx >> 8;
                const int jp = (idx & 255) << 1;       // even j
                const int b = b0 + r;
                const int tk = tok[b];                 // same-block producer (plain ok)
                const float* __restrict__ wr = WihT + (size_t)tk * FH;
                const size_t base = (size_t)b * FH;
                float g4[4][2];
#pragma unroll
                for (int gi_ = 0; gi_ < 4; ++gi_) {
                    const int off = gi_ * 512 + jp;
#pragma unroll
                    for (int e = 0; e < 2; ++e)
                        g4[gi_][e] = ALOADF(&g0[base + off + e]) + ALOADF(&g1[base + off + e])
                                   + wr[off + e] + bsum[off + e];
                }
                const float co0 = cbuf[(size_t)b * H_ + jp];
                const float co1 = cbuf[(size_t)b * H_ + jp + 1];
                float cn0 = sigf(g4[1][0]) * co0 + sigf(g4[0][0]) * tanhf(g4[2][0]);
                float cn1 = sigf(g4[1][1]) * co1 + sigf(g4[0][1]) * tanhf(g4[2][1]);
                float hn0 = sigf(g4[3][0]) * tanhf(cn0);
                float hn1 = sigf(g4[3][1]) * tanhf(cn1);
                cbuf[(size_t)b * H_ + jp]     = cn0;
                cbuf[(size_t)b * H_ + jp + 1] = cn1;
                hs[r][jp] = hn0; hs[r][jp + 1] = hn1;
                unsigned short hi0 = f2bf(hn0), hi1 = f2bf(hn1);
                unsigned short lo0 = f2bf(hn0 - bf2f(hi0)), lo1 = f2bf(hn1 - bf2f(hi1));
                short* ar = acat + (size_t)b * KC;
                const unsigned hh = (unsigned)hi0 | ((unsigned)hi1 << 16);
                const unsigned ll = (unsigned)lo0 | ((unsigned)lo1 << 16);
                ASTORE32(ar + jp, hh);
                ASTORE32(ar + 512 + jp, hh);
                ASTORE32(ar + 1024 + jp, ll);
            }
            __syncthreads();

            // ---- phase 2: p = relu(h @ W1^T + b1), 200 jobs = (gen, k-half), 8 rows each
            if (tid < 200) {
                const int gi2 = tid % 100, kq = tid / 100;
                const float4* __restrict__ wrow = (const float4*)(W1 + (size_t)gi2 * H_ + kq * 256);
                float a[8];
#pragma unroll
                for (int r = 0; r < 8; ++r) a[r] = 0.f;
                for (int k4 = 0; k4 < 64; k4++) {
                    float4 wv = wrow[k4];
#pragma unroll
                    for (int r = 0; r < 8; ++r) {
                        float4 h = *(const float4*)&hs[r][kq * 256 + k4 * 4];
                        a[r] += wv.x * h.x + wv.y * h.y + wv.z * h.z + wv.w * h.w;
                    }
                }
#pragma unroll
                for (int r = 0; r < 8; ++r) pps[kq][r][gi2] = a[r];
            }
            __syncthreads();
            for (int idx = tid; idx < 800; idx += 256) {
                const int r = idx / 100, gi2 = idx % 100;
                float v = b1[gi2] + pps[0][r][gi2] + pps[1][r][gi2];
                ps[r][gi2] = v > 0.f ? v : 0.f;
            }
            __syncthreads();

            // ---- phase 3: logits = p @ W2^T + b2; thread: 4 vocab rows x 8 batch rows
            const int v0 = tid * 4;
            float accv[4][8];  // [vi][r]
#pragma unroll
            for (int vi = 0; vi < 4; vi++) {
                const float bb = b2[v0 + vi];
#pragma unroll
                for (int r = 0; r < 8; r++) accv[vi][r] = bb;
            }
            for (int j4 = 0; j4 < 25; j4++) {
                float4 p[8];
#pragma unroll
                for (int r = 0; r < 8; ++r) p[r] = *(const float4*)&ps[r][j4 * 4];
#pragma unroll
                for (int vi = 0; vi < 4; vi++) {
                    float4 wv = *(const float4*)&W2[(size_t)(v0 + vi) * GEN_ + j4 * 4];
#pragma unroll
                    for (int r = 0; r < 8; ++r)
                        accv[vi][r] += wv.x * p[r].x + wv.y * p[r].y + wv.z * p[r].z + wv.w * p[r].w;
                }
            }

            // ---- per-row max + argmax (first-index tie-break)
            float lmax[8]; int lidx[8];
#pragma unroll
            for (int r = 0; r < 8; r++) {
                lmax[r] = accv[0][r]; lidx[r] = v0;
#pragma unroll
                for (int vi = 1; vi < 4; vi++)
                    if (accv[vi][r] > lmax[r]) { lmax[r] = accv[vi][r]; lidx[r] = v0 + vi; }
            }
#pragma unroll
            for (int off = 32; off; off >>= 1) {
#pragma unroll
                for (int r = 0; r < 8; r++) {
                    float ov = __shfl_xor(lmax[r], off);
                    int   oi = __shfl_xor(lidx[r], off);
                    if (ov > lmax[r] || (ov == lmax[r] && oi < lidx[r])) { lmax[r] = ov; lidx[r] = oi; }
                }
            }
            if (lane == 0) {
#pragma unroll
                for (int r = 0; r < 8; r++) { red[r][w] = lmax[r]; redi[r][w] = lidx[r]; }
            }
            __syncthreads();
            float rmax[8]; int ridx[8];
#pragma unroll
            for (int r = 0; r < 8; r++) {
                rmax[r] = red[r][0]; ridx[r] = redi[r][0];
#pragma unroll
                for (int wv2 = 1; wv2 < 4; wv2++)
                    if (red[r][wv2] > rmax[r] || (red[r][wv2] == rmax[r] && redi[r][wv2] < ridx[r])) {
                        rmax[r] = red[r][wv2]; ridx[r] = redi[r][wv2];
                    }
            }
            __syncthreads();  // before reusing red[]

            // ---- sum(exp(x - max))
            float ls[8];
#pragma unroll
            for (int r = 0; r < 8; r++)
                ls[r] = expf(accv[0][r] - rmax[r]) + expf(accv[1][r] - rmax[r]) +
                        expf(accv[2][r] - rmax[r]) + expf(accv[3][r] - rmax[r]);
#pragma unroll
            for (int off = 32; off; off >>= 1) {
#pragma unroll
                for (int r = 0; r < 8; r++) ls[r] += __shfl_xor(ls[r], off);
            }
            if (lane == 0) {
#pragma unroll
                for (int r = 0; r < 8; r++) red[r][w] = ls[r];
            }
            __syncthreads();
#pragma unroll
            for (int r = 0; r < 8; r++) {
                const float logZ = rmax[r] + logf(red[r][0] + red[r][1] + red[r][2] + red[r][3]);
                float4 o;
                o.x = accv[0][r] - logZ; o.y = accv[1][r] - logZ;
                o.z = accv[2][r] - logZ; o.w = accv[3][r] - logZ;
                *(float4*)&outt[(size_t)(b0 + r) * V_ + v0] = o;
            }
            if (tid == 0) {
#pragma unroll
                for (int r = 0; r < 8; r++) tok[b0 + r] = ridx[r];
            }
        }
        if (t < T_ - 1) { bar_target += 128; gsync(gbar, bar_target); }
    }
}

// ---------------- host ----------------
extern "C" void kernel_launch(void* const* d_in, const int* in_sizes, int n_in,
                              void* d_out, int out_size, void* d_ws, size_t ws_size,
                              hipStream_t stream) {
    const float* input   = (const float*)d_in[0];
    const float* onehots = (const float*)d_in[1];
    // d_in[2] digits (unused), d_in[3] teacher (==0, free-running path hardcoded)
    const float* Wh  = (const float*)d_in[4];
    const float* bh  = (const float*)d_in[5];
    const float* Wc  = (const float*)d_in[6];
    const float* bc  = (const float*)d_in[7];
    const float* Wih = (const float*)d_in[8];
    const float* Whh = (const float*)d_in[9];
    const float* bih = (const float*)d_in[10];
    const float* bhh = (const float*)d_in[11];
    const float* W1  = (const float*)d_in[12];
    const float* b1  = (const float*)d_in[13];
    const float* W2  = (const float*)d_in[14];
    const float* b2  = (const float*)d_in[15];
    float* out = (float*)d_out;

    char* ws = (char*)d_ws;
    float* gpart = (float*)(ws + OFF_G);
    float* cbuf  = (float*)(ws + OFF_C);
    float* WihT  = (float*)(ws + OFF_WIHT);
    short* acat  = (short*)(ws + OFF_ACAT);
    short* bcat  = (short*)(ws + OFF_BCAT);
    float* bsum  = (float*)(ws + OFF_BSUM);
    int*   tok   = (int*)(ws + OFF_TOK);
    unsigned* gbar = (unsigned*)(ws + OFF_BAR);

    k_init<<<(B_ * H_) / 256, 256, 0, stream>>>(input, Wh, bh, Wc, bc, bih, bhh, cbuf, acat, bsum, gbar);
    k_tok0<<<(B_ * V_) / 256, 256, 0, stream>>>(onehots, tok);
    k_transpose<<<(V_ * FH) / 256, 256, 0, stream>>>(Wih, WihT);
    k_prep<<<(FH * H_) / 256, 256, 0, stream>>>(Whh, bcat);

    k_main<<<128, 256, 0, stream>>>(bcat, acat, gpart, cbuf, WihT, bsum, tok,
                                    W1, b1, W2, b2, out, gbar);
}

// Round 5
// 7624.190 us; speedup vs baseline: 1.6041x; 1.6041x over previous
//
#include <hip/hip_runtime.h>
#include <math.h>

#define B_   1024
#define T_   64
#define H_   512
#define V_   1024
#define GEN_ 100
#define FH   2048   // 4*H
#define KC   1536   // 3*H concatenated-K for bf16x2 compensated GEMM

// ---------------- workspace layout (bytes) ----------------
static constexpr size_t MB = 1024ull * 1024;
static constexpr size_t OFF_G    = 0;            // 2 * B*FH fp32 split-K partials (16 MB)
static constexpr size_t OFF_C    = 16 * MB;      // B*H fp32 (2 MB)
static constexpr size_t OFF_WIHT = 18 * MB;      // V*FH fp32 (8 MB)
static constexpr size_t OFF_ACAT = 26 * MB;      // B*KC bf16 (3 MB)   [h_hi | h_hi | h_lo]
static constexpr size_t OFF_BCAT = 29 * MB;      // FH*KC bf16 (6 MB)  [W_hi | W_lo | W_hi]
static constexpr size_t OFF_BSUM = 35 * MB;      // FH fp32
static constexpr size_t OFF_TOK  = 35 * MB + 8192;   // B int (4 KB)
static constexpr size_t OFF_BAR  = 35 * MB + 16384;  // grid-barrier counter

typedef __attribute__((ext_vector_type(8))) short short8v;
typedef __attribute__((ext_vector_type(4))) float f32x4;

__device__ __forceinline__ float sigf(float x) { return 1.0f / (1.0f + expf(-x)); }

__device__ __forceinline__ unsigned short f2bf(float f) {  // RNE fp32 -> bf16
    unsigned int u = __float_as_uint(f);
    return (unsigned short)((u + 0x7FFFu + ((u >> 16) & 1u)) >> 16);
}
__device__ __forceinline__ float bf2f(unsigned short b) {
    return __uint_as_float(((unsigned int)b) << 16);
}

__device__ __forceinline__ void gload16(const void* g, void* l) {
    __builtin_amdgcn_global_load_lds((const __attribute__((address_space(1))) void*)g,
                                     (__attribute__((address_space(3))) void*)l, 16, 0, 0);
}

// manual grid barrier (round-3-proven coherence, cheaper issue): __syncthreads
// drains all vector mem ops into L2; tid0 does release fence (buffer_wbl2 ->
// dirty L2 visible at LLC), arrives, spins, acquire fence (buffer_inv -> L1/L2
// drop stale lines), then block-wide barrier. One fence pair per BLOCK, not per
// wave. Deadlock-free: grid 256 <= co-resident capacity (LDS 45KB -> >=2
// blocks/CU -> capacity >= 512).
__device__ __forceinline__ void gsync(unsigned* cnt, unsigned target) {
    __syncthreads();
    if (threadIdx.x == 0) {
        __threadfence();   // release
        __hip_atomic_fetch_add(cnt, 1u, __ATOMIC_RELAXED, __HIP_MEMORY_SCOPE_AGENT);
        while (__hip_atomic_load(cnt, __ATOMIC_RELAXED, __HIP_MEMORY_SCOPE_AGENT) < target)
            __builtin_amdgcn_s_sleep(2);
        __threadfence();   // acquire
    }
    __syncthreads();
}

// ---------------- setup kernels ----------------
__global__ __launch_bounds__(256) void k_init(const float* __restrict__ input,
                                              const float* __restrict__ Wh, const float* __restrict__ bh,
                                              const float* __restrict__ Wc, const float* __restrict__ bc,
                                              const float* __restrict__ bih, const float* __restrict__ bhh,
                                              float* __restrict__ cbuf, short* __restrict__ acat,
                                              float* __restrict__ bsum, unsigned* __restrict__ gbar) {
    int idx = blockIdx.x * 256 + threadIdx.x;  // over B*H
    int b = idx >> 9, j = idx & (H_ - 1);
    float x = input[b];
    float h0 = x * Wh[j] + bh[j];
    cbuf[idx] = x * Wc[j] + bc[j];
    unsigned short hi = f2bf(h0);
    unsigned short lo = f2bf(h0 - bf2f(hi));
    short* ar = acat + (size_t)b * KC;
    ar[j] = (short)hi; ar[512 + j] = (short)hi; ar[1024 + j] = (short)lo;
    if (idx < FH) bsum[idx] = bih[idx] + bhh[idx];
    if (idx == 0) *gbar = 0u;
}

__global__ __launch_bounds__(256) void k_tok0(const float* __restrict__ onehots, int* __restrict__ tok) {
    int idx = blockIdx.x * 256 + threadIdx.x;  // over B*V
    int b = idx >> 10, v = idx & (V_ - 1);
    if (onehots[(size_t)b * (T_ * V_) + v] > 0.5f) tok[b] = v;  // exact one-hot: single writer
}

__global__ __launch_bounds__(256) void k_transpose(const float* __restrict__ Wih, float* __restrict__ WihT) {
    int idx = blockIdx.x * 256 + threadIdx.x;  // over V*FH
    int v = idx >> 11, n = idx & (FH - 1);
    WihT[idx] = Wih[(size_t)n * V_ + v];
}

__global__ __launch_bounds__(256) void k_prep(const float* __restrict__ Whh, short* __restrict__ bcat) {
    int idx = blockIdx.x * 256 + threadIdx.x;  // over FH*H
    int n = idx >> 9, k = idx & (H_ - 1);
    float w = Whh[idx];
    unsigned short hi = f2bf(w);
    unsigned short lo = f2bf(w - bf2f(hi));
    short* br = bcat + (size_t)n * KC;
    br[k] = (short)hi; br[512 + k] = (short)lo; br[1024 + k] = (short)hi;
}

// ---------------- persistent kernel: whole T-loop ----------------
// 256 blocks x 512 threads (8 waves). GEMM role: one (m-tile 128, n-tile 128,
// k-half 768) slice; wave w owns 16 n-rows -> W-slice in 24 short8v = 96 VGPR.
// A staged to LDS via global_load_lds (XOR-chunk pre-swizzled source).
// Head role: 4 batch rows b0 = bj*4 (math order identical to round-0 k_head).
__global__ __launch_bounds__(512) void k_main(const short* __restrict__ bcat,
                                              short* __restrict__ acat,
                                              float* __restrict__ gpart,
                                              float* __restrict__ cbuf,
                                              const float* __restrict__ WihT,
                                              const float* __restrict__ bsum,
                                              int* __restrict__ tok,
                                              const float* __restrict__ W1, const float* __restrict__ b1,
                                              const float* __restrict__ W2, const float* __restrict__ b2,
                                              float* __restrict__ outbase,
                                              unsigned* __restrict__ gbar) {
    const int tid = threadIdx.x;
    const int lane = tid & 63, wv = tid >> 6;      // 8 waves
    const int quad = lane >> 4, l15 = lane & 15;
    const int bj = blockIdx.x;  // [0,256)

    // GEMM role: z = bj>>7 (k-half), n-tile = (bj>>3)&15, m-tile = bj&7
    const int z  = bj >> 7;
    const int n0 = ((bj >> 3) & 15) * 128;
    const int m0 = (bj & 7) * 128;
    const int k0 = z * 768;
    float* __restrict__ gout = gpart + (size_t)z * (B_ * FH);

    // head role: 4 rows
    const int b0 = bj * 4;

    __shared__ __align__(16) short As[2][8192];  // 2 x 16 KB A dbuf, XOR-chunk-swizzled
    __shared__ float hs[4][512];                 // 8 KB
    __shared__ float pps[2][4][104];             // 3.3 KB
    __shared__ float ps[4][104];                 // 1.7 KB
    __shared__ float red[4][8];
    __shared__ int  redi[4][8];
    // total ~45.5 KB -> >=2 blocks/CU capacity (spin barrier safe), 3 by LDS

    // ---- W-slice into registers (once): wave wv owns n-rows [wv*16, wv*16+16)
    short8v wreg[24];
    {
        const short* wb = bcat + (size_t)(n0 + wv * 16 + l15) * KC + k0 + quad * 8;
#pragma unroll
        for (int kk = 0; kk < 24; ++kk)
            wreg[kk] = *(const short8v*)(wb + kk * 32);
    }

    // ---- A staging geometry: wave wv stages rows [wv*16, wv*16+16) in 2 instrs
    // of 8 rows; global source pre-swizzled so linear LDS dst == swizzled layout.
    const int srow = lane >> 3;                  // row within 8-row group
    const int schunk = (lane & 7) ^ srow;        // global 16B-chunk index (XOR swizzle)
    const size_t lanoff = (size_t)srow * KC + (size_t)schunk * 8;
    const short* aw0 = acat + (size_t)(m0 + wv * 16 + srow) * KC + k0 + (size_t)schunk * 8 - lanoff + lanoff; // rows wv*16+srow
    const short* awu0 = acat + (size_t)(m0 + wv * 16) * KC + k0 + lanoff;       // u=0: rows wv*16 + srow
    const short* awu1 = acat + (size_t)(m0 + wv * 16 + 8) * KC + k0 + lanoff;   // u=1: rows wv*16+8 + srow
    (void)aw0;

    int raA[8], rxA[8];
#pragma unroll
    for (int mi = 0; mi < 8; ++mi) { int rm = mi * 16 + l15; raA[mi] = rm * 8; rxA[mi] = rm & 7; }

    unsigned bar_target = 0;

#pragma unroll 1
    for (int t = 0; t < T_; ++t) {
        // ================= segment 1: gates GEMM (W in VGPRs) =================
        f32x4 acc[8];
#pragma unroll
        for (int mi = 0; mi < 8; ++mi) acc[mi] = (f32x4){0.f, 0.f, 0.f, 0.f};

        // prologue: stage k-iter 0 into buf0
        gload16(awu0, &As[0][wv * 1024]);
        gload16(awu1, &As[0][wv * 1024 + 512]);
        __syncthreads();
#pragma unroll
        for (int it = 0; it < 12; ++it) {
            if (it < 11) {  // prefetch next k-iter into the other buffer
                const int nb = (it + 1) & 1;
                gload16(awu0 + (it + 1) * 64, &As[nb][wv * 1024]);
                gload16(awu1 + (it + 1) * 64, &As[nb][wv * 1024 + 512]);
            }
            const short* Ab = &As[it & 1][0];
#pragma unroll
            for (int kh = 0; kh < 2; ++kh) {
                const int c = kh * 4 + quad;
                short8v av[8];
#pragma unroll
                for (int mi = 0; mi < 8; ++mi)
                    av[mi] = *(const short8v*)&Ab[(raA[mi] + (c ^ rxA[mi])) * 8];
#pragma unroll
                for (int mi = 0; mi < 8; ++mi)
                    acc[mi] = __builtin_amdgcn_mfma_f32_16x16x32_bf16(av[mi], wreg[it * 2 + kh], acc[mi], 0, 0, 0);
            }
            __syncthreads();  // drains vmcnt (prefetch) + guards buffer reuse
        }
        // epilogue: C/D layout col(n)=lane&15, row(m)=quad*4+reg  [m89-verified]
#pragma unroll
        for (int mi = 0; mi < 8; ++mi) {
            const int m = m0 + mi * 16 + quad * 4;
            const int n = n0 + wv * 16 + l15;
            float* gp = gout + (size_t)m * FH + n;
#pragma unroll
            for (int r = 0; r < 4; ++r) gp[(size_t)r * FH] = acc[mi][r];
        }
        bar_target += 256; gsync(gbar, bar_target);

        // ================= segment 2: cell + head + log_softmax + argmax (4 rows) =================
        {
            const float* __restrict__ g0 = gpart;
            const float* __restrict__ g1 = gpart + (size_t)B_ * FH;
            float* __restrict__ outt = outbase + (size_t)t * ((size_t)B_ * V_);

            // ---- phase 1: LSTM cell; pair-of-j so acat writes pack to u32
            {
                const int idx = tid;                   // 0..511 covers 4 rows x 256 pairs... need 1024 jobs
#pragma unroll
                for (int ii = 0; ii < 2; ++ii) {
                    const int job = idx + ii * 512;    // 0..1023
                    const int r = job >> 8;
                    const int jp = (job & 255) << 1;   // even j
                    const int b = b0 + r;
                    const int tk = tok[b];
                    const float* __restrict__ wr = WihT + (size_t)tk * FH;
                    const size_t base = (size_t)b * FH;
                    float g4[4][2];
#pragma unroll
                    for (int gi_ = 0; gi_ < 4; ++gi_) {
                        const int off = gi_ * 512 + jp;
                        float2 a0 = *(const float2*)&g0[base + off];
                        float2 a1 = *(const float2*)&g1[base + off];
                        float2 wv2 = *(const float2*)&wr[off];
                        float2 bs = *(const float2*)&bsum[off];
                        g4[gi_][0] = a0.x + a1.x + wv2.x + bs.x;
                        g4[gi_][1] = a0.y + a1.y + wv2.y + bs.y;
                    }
                    float2 co = *(const float2*)&cbuf[(size_t)b * H_ + jp];
                    float cn0 = sigf(g4[1][0]) * co.x + sigf(g4[0][0]) * tanhf(g4[2][0]);
                    float cn1 = sigf(g4[1][1]) * co.y + sigf(g4[0][1]) * tanhf(g4[2][1]);
                    float hn0 = sigf(g4[3][0]) * tanhf(cn0);
                    float hn1 = sigf(g4[3][1]) * tanhf(cn1);
                    *(float2*)&cbuf[(size_t)b * H_ + jp] = make_float2(cn0, cn1);
                    hs[r][jp] = hn0; hs[r][jp + 1] = hn1;
                    unsigned short hi0 = f2bf(hn0), hi1 = f2bf(hn1);
                    unsigned short lo0 = f2bf(hn0 - bf2f(hi0)), lo1 = f2bf(hn1 - bf2f(hi1));
                    short* ar = acat + (size_t)b * KC;
                    const unsigned hh = (unsigned)hi0 | ((unsigned)hi1 << 16);
                    const unsigned ll = (unsigned)lo0 | ((unsigned)lo1 << 16);
                    *(unsigned*)&ar[jp] = hh;
                    *(unsigned*)&ar[512 + jp] = hh;
                    *(unsigned*)&ar[1024 + jp] = ll;
                }
            }
            __syncthreads();

            // ---- phase 2: p = relu(h @ W1^T + b1), 200 jobs = (gen, k-half) [round-0 order]
            if (tid < 200) {
                const int gi2 = tid % 100, kq = tid / 100;
                const float4* __restrict__ wrow = (const float4*)(W1 + (size_t)gi2 * H_ + kq * 256);
                float a0 = 0.f, a1 = 0.f, a2 = 0.f, a3 = 0.f;
                for (int k4 = 0; k4 < 64; k4++) {
                    float4 wv4 = wrow[k4];
                    float4 h0 = *(const float4*)&hs[0][kq * 256 + k4 * 4];
                    float4 h1 = *(const float4*)&hs[1][kq * 256 + k4 * 4];
                    float4 h2 = *(const float4*)&hs[2][kq * 256 + k4 * 4];
                    float4 h3 = *(const float4*)&hs[3][kq * 256 + k4 * 4];
                    a0 += wv4.x * h0.x + wv4.y * h0.y + wv4.z * h0.z + wv4.w * h0.w;
                    a1 += wv4.x * h1.x + wv4.y * h1.y + wv4.z * h1.z + wv4.w * h1.w;
                    a2 += wv4.x * h2.x + wv4.y * h2.y + wv4.z * h2.z + wv4.w * h2.w;
                    a3 += wv4.x * h3.x + wv4.y * h3.y + wv4.z * h3.z + wv4.w * h3.w;
                }
                pps[kq][0][gi2] = a0; pps[kq][1][gi2] = a1;
                pps[kq][2][gi2] = a2; pps[kq][3][gi2] = a3;
            }
            __syncthreads();
            if (tid < 400) {
                const int r = tid / 100, gi2 = tid % 100;
                float v = b1[gi2] + pps[0][r][gi2] + pps[1][r][gi2];
                ps[r][gi2] = v > 0.f ? v : 0.f;
            }
            __syncthreads();

            // ---- phase 3: logits = p @ W2^T + b2; thread: 2 vocab rows x 4 batch rows
            const int v0 = tid * 2;
            float accv[2][4];  // [vi][r]; per-logit chain identical to round-0
#pragma unroll
            for (int vi = 0; vi < 2; vi++) {
                const float bb = b2[v0 + vi];
#pragma unroll
                for (int r = 0; r < 4; r++) accv[vi][r] = bb;
            }
            for (int j4 = 0; j4 < 25; j4++) {
                float4 p0 = *(const float4*)&ps[0][j4 * 4];
                float4 p1 = *(const float4*)&ps[1][j4 * 4];
                float4 p2 = *(const float4*)&ps[2][j4 * 4];
                float4 p3 = *(const float4*)&ps[3][j4 * 4];
#pragma unroll
                for (int vi = 0; vi < 2; vi++) {
                    float4 wv4 = *(const float4*)&W2[(size_t)(v0 + vi) * GEN_ + j4 * 4];
                    accv[vi][0] += wv4.x * p0.x + wv4.y * p0.y + wv4.z * p0.z + wv4.w * p0.w;
                    accv[vi][1] += wv4.x * p1.x + wv4.y * p1.y + wv4.z * p1.z + wv4.w * p1.w;
                    accv[vi][2] += wv4.x * p2.x + wv4.y * p2.y + wv4.z * p2.z + wv4.w * p2.w;
                    accv[vi][3] += wv4.x * p3.x + wv4.y * p3.y + wv4.z * p3.z + wv4.w * p3.w;
                }
            }

            // ---- per-row max + argmax (first-index tie-break)
            float lmax[4]; int lidx[4];
#pragma unroll
            for (int r = 0; r < 4; r++) {
                lmax[r] = accv[0][r]; lidx[r] = v0;
                if (accv[1][r] > lmax[r]) { lmax[r] = accv[1][r]; lidx[r] = v0 + 1; }
            }
#pragma unroll
            for (int off = 32; off; off >>= 1) {
#pragma unroll
                for (int r = 0; r < 4; r++) {
                    float ov = __shfl_xor(lmax[r], off);
                    int   oi = __shfl_xor(lidx[r], off);
                    if (ov > lmax[r] || (ov == lmax[r] && oi < lidx[r])) { lmax[r] = ov; lidx[r] = oi; }
                }
            }
            if (lane == 0) {
#pragma unroll
                for (int r = 0; r < 4; r++) { red[r][wv] = lmax[r]; redi[r][wv] = lidx[r]; }
            }
            __syncthreads();
            float rmax[4]; int ridx[4];
#pragma unroll
            for (int r = 0; r < 4; r++) {
                rmax[r] = red[r][0]; ridx[r] = redi[r][0];
#pragma unroll
                for (int w2 = 1; w2 < 8; w2++)
                    if (red[r][w2] > rmax[r] || (red[r][w2] == rmax[r] && redi[r][w2] < ridx[r])) {
                        rmax[r] = red[r][w2]; ridx[r] = redi[r][w2];
                    }
            }
            __syncthreads();  // before reusing red[]

            // ---- sum(exp(x - max))
            float ls[4];
#pragma unroll
            for (int r = 0; r < 4; r++)
                ls[r] = expf(accv[0][r] - rmax[r]) + expf(accv[1][r] - rmax[r]);
#pragma unroll
            for (int off = 32; off; off >>= 1) {
#pragma unroll
                for (int r = 0; r < 4; r++) ls[r] += __shfl_xor(ls[r], off);
            }
            if (lane == 0) {
#pragma unroll
                for (int r = 0; r < 4; r++) red[r][wv] = ls[r];
            }
            __syncthreads();
#pragma unroll
            for (int r = 0; r < 4; r++) {
                float tot = red[r][0];
#pragma unroll
                for (int w2 = 1; w2 < 8; w2++) tot += red[r][w2];
                const float logZ = rmax[r] + logf(tot);
                float2 o;
                o.x = accv[0][r] - logZ; o.y = accv[1][r] - logZ;
                *(float2*)&outt[(size_t)(b0 + r) * V_ + v0] = o;
            }
            if (tid == 0) {
#pragma unroll
                for (int r = 0; r < 4; r++) tok[b0 + r] = ridx[r];
            }
        }
        if (t < T_ - 1) { bar_target += 256; gsync(gbar, bar_target); }
    }
}

// ---------------- host ----------------
extern "C" void kernel_launch(void* const* d_in, const int* in_sizes, int n_in,
                              void* d_out, int out_size, void* d_ws, size_t ws_size,
                              hipStream_t stream) {
    const float* input   = (const float*)d_in[0];
    const float* onehots = (const float*)d_in[1];
    // d_in[2] digits (unused), d_in[3] teacher (==0, free-running path hardcoded)
    const float* Wh  = (const float*)d_in[4];
    const float* bh  = (const float*)d_in[5];
    const float* Wc  = (const float*)d_in[6];
    const float* bc  = (const float*)d_in[7];
    const float* Wih = (const float*)d_in[8];
    const float* Whh = (const float*)d_in[9];
    const float* bih = (const float*)d_in[10];
    const float* bhh = (const float*)d_in[11];
    const float* W1  = (const float*)d_in[12];
    const float* b1  = (const float*)d_in[13];
    const float* W2  = (const float*)d_in[14];
    const float* b2  = (const float*)d_in[15];
    float* out = (float*)d_out;

    char* ws = (char*)d_ws;
    float* gpart = (float*)(ws + OFF_G);
    float* cbuf  = (float*)(ws + OFF_C);
    float* WihT  = (float*)(ws + OFF_WIHT);
    short* acat  = (short*)(ws + OFF_ACAT);
    short* bcat  = (short*)(ws + OFF_BCAT);
    float* bsum  = (float*)(ws + OFF_BSUM);
    int*   tok   = (int*)(ws + OFF_TOK);
    unsigned* gbar = (unsigned*)(ws + OFF_BAR);

    k_init<<<(B_ * H_) / 256, 256, 0, stream>>>(input, Wh, bh, Wc, bc, bih, bhh, cbuf, acat, bsum, gbar);
    k_tok0<<<(B_ * V_) / 256, 256, 0, stream>>>(onehots, tok);
    k_transpose<<<(V_ * FH) / 256, 256, 0, stream>>>(Wih, WihT);
    k_prep<<<(FH * H_) / 256, 256, 0, stream>>>(Whh, bcat);

    k_main<<<256, 512, 0, stream>>>(bcat, acat, gpart, cbuf, WihT, bsum, tok,
                                    W1, b1, W2, b2, out, gbar);
}

// Round 6
// 5142.650 us; speedup vs baseline: 2.3781x; 1.4825x over previous
//
#include <hip/hip_runtime.h>
#include <math.h>

#define B_   1024
#define T_   64
#define H_   512
#define V_   1024
#define GEN_ 100
#define FH   2048   // 4*H
#define KC   1536   // 3*H concatenated-K for bf16x2 compensated GEMM

// ---------------- workspace layout (bytes) ----------------
static constexpr size_t MB = 1024ull * 1024;
static constexpr size_t OFF_G    = 0;            // 2 * B*FH fp32 split-K partials (16 MB)
static constexpr size_t OFF_C    = 16 * MB;      // B*H fp32 (2 MB)
static constexpr size_t OFF_WIHT = 18 * MB;      // V*FH fp32 (8 MB)
static constexpr size_t OFF_ACAT = 26 * MB;      // B*KC bf16 (3 MB)   [h_hi | h_hi | h_lo]
static constexpr size_t OFF_BCAT = 29 * MB;      // FH*KC bf16 (6 MB)  [W_hi | W_lo | W_hi]
static constexpr size_t OFF_BSUM = 35 * MB;      // FH fp32
static constexpr size_t OFF_TOK  = 35 * MB + 8192;  // B int

typedef __attribute__((ext_vector_type(8))) short short8v;
typedef __attribute__((ext_vector_type(4))) float f32x4;

__device__ __forceinline__ float sigf(float x) { return 1.0f / (1.0f + expf(-x)); }

__device__ __forceinline__ unsigned short f2bf(float f) {  // RNE fp32 -> bf16
    unsigned int u = __float_as_uint(f);
    return (unsigned short)((u + 0x7FFFu + ((u >> 16) & 1u)) >> 16);
}
__device__ __forceinline__ float bf2f(unsigned short b) {
    return __uint_as_float(((unsigned int)b) << 16);
}

__device__ __forceinline__ void gload16(const void* g, void* l) {
    __builtin_amdgcn_global_load_lds((const __attribute__((address_space(1))) void*)g,
                                     (__attribute__((address_space(3))) void*)l, 16, 0, 0);
}

// ---------------- setup kernels ----------------
__global__ __launch_bounds__(256) void k_init(const float* __restrict__ input,
                                              const float* __restrict__ Wh, const float* __restrict__ bh,
                                              const float* __restrict__ Wc, const float* __restrict__ bc,
                                              const float* __restrict__ bih, const float* __restrict__ bhh,
                                              float* __restrict__ cbuf, short* __restrict__ acat,
                                              float* __restrict__ bsum) {
    int idx = blockIdx.x * 256 + threadIdx.x;  // over B*H
    int b = idx >> 9, j = idx & (H_ - 1);
    float x = input[b];
    float h0 = x * Wh[j] + bh[j];
    cbuf[idx] = x * Wc[j] + bc[j];
    unsigned short hi = f2bf(h0);
    unsigned short lo = f2bf(h0 - bf2f(hi));
    short* ar = acat + (size_t)b * KC;
    ar[j] = (short)hi; ar[512 + j] = (short)hi; ar[1024 + j] = (short)lo;
    if (idx < FH) bsum[idx] = bih[idx] + bhh[idx];
}

__global__ __launch_bounds__(256) void k_tok0(const float* __restrict__ onehots, int* __restrict__ tok) {
    int idx = blockIdx.x * 256 + threadIdx.x;  // over B*V
    int b = idx >> 10, v = idx & (V_ - 1);
    if (onehots[(size_t)b * (T_ * V_) + v] > 0.5f) tok[b] = v;  // exact one-hot: single writer
}

__global__ __launch_bounds__(256) void k_transpose(const float* __restrict__ Wih, float* __restrict__ WihT) {
    int idx = blockIdx.x * 256 + threadIdx.x;  // over V*FH
    int v = idx >> 11, n = idx & (FH - 1);
    WihT[idx] = Wih[(size_t)n * V_ + v];
}

__global__ __launch_bounds__(256) void k_prep(const float* __restrict__ Whh, short* __restrict__ bcat) {
    int idx = blockIdx.x * 256 + threadIdx.x;  // over FH*H
    int n = idx >> 9, k = idx & (H_ - 1);
    float w = Whh[idx];
    unsigned short hi = f2bf(w);
    unsigned short lo = f2bf(w - bf2f(hi));
    short* br = bcat + (size_t)n * KC;
    br[k] = (short)hi; br[512 + k] = (short)lo; br[1024 + k] = (short)hi;
}

// ---------------- K1: gpart[z] = partial of Acat @ Bcat^T (bf16 MFMA, split-K=2) ----------------
// grid (16 n-tiles, 16 m-tiles, 2 k-splits) = 512 blocks (2 blocks/CU), 256 threads,
// 64x128 (m x n) tile, BK=64. LDS XOR chunk swizzle: slot(row, cs) holds chunk cs ^ (row&7).
__global__ __launch_bounds__(256) void k_gates(const short* __restrict__ Acat,
                                               const short* __restrict__ Bcat,
                                               float* __restrict__ gpart) {
    const int tid = threadIdx.x;
    const int lane = tid & 63, w = tid >> 6;
    const int n0 = blockIdx.x * 128;
    const int m0 = blockIdx.y * 64;
    const int k0 = blockIdx.z * (KC / 2);
    float* __restrict__ gout = gpart + (size_t)blockIdx.z * (B_ * FH);

    __shared__ __align__(16) short As[64 * 64];   // 8 KB, [row][chunk] swizzled
    __shared__ __align__(16) short Bs[128 * 64];  // 16 KB

    f32x4 acc[4][2];
#pragma unroll
    for (int i = 0; i < 4; i++)
#pragma unroll
        for (int j = 0; j < 2; j++) acc[i][j] = (f32x4){0.f, 0.f, 0.f, 0.f};

    const int quad = lane >> 4, l15 = lane & 15;

    // staging geometry: gload16 writes 8 rows x 64 shorts per instr.
    const int srow = lane >> 3;                      // row within 8-row group
    const int schunk = (lane & 7) ^ srow;            // global 16B-chunk index (XOR swizzle)
    const size_t lanoff = (size_t)srow * KC + (size_t)schunk * 8;  // bf16 elements

    // A: wave w stages rows [w*16, w*16+16) in 2 instrs; B: rows [w*32, w*32+32) in 4.
    const short* aw = Acat + (size_t)(m0 + w * 16) * KC + k0 + lanoff;
    const short* bw = Bcat + (size_t)(n0 + w * 32) * KC + k0 + lanoff;
    short* lA = &As[w * 16 * 64];
    short* lB = &Bs[w * 32 * 64];

    // fragment row constants
    int raA[4], rxA[4], raB[2], rxB[2];
#pragma unroll
    for (int i = 0; i < 4; i++) { int rm = i * 16 + l15; raA[i] = rm * 8; rxA[i] = rm & 7; }
#pragma unroll
    for (int j = 0; j < 2; j++) { int rn = w * 32 + j * 16 + l15; raB[j] = rn * 8; rxB[j] = rn & 7; }

    for (int it = 0; it < (KC / 2) / 64; ++it) {
        const short* ga = aw + it * 64;
        const short* gb = bw + it * 64;
#pragma unroll
        for (int u = 0; u < 2; ++u) gload16(ga + (size_t)(u * 8) * KC, lA + u * 512);
#pragma unroll
        for (int u = 0; u < 4; ++u) gload16(gb + (size_t)(u * 8) * KC, lB + u * 512);
        __syncthreads();
#pragma unroll
        for (int kh = 0; kh < 2; ++kh) {
            const int c = kh * 4 + quad;
            short8v av[4], bv[2];
#pragma unroll
            for (int i = 0; i < 4; i++) av[i] = *(const short8v*)&As[(raA[i] + (c ^ rxA[i])) * 8];
#pragma unroll
            for (int j = 0; j < 2; j++) bv[j] = *(const short8v*)&Bs[(raB[j] + (c ^ rxB[j])) * 8];
#pragma unroll
            for (int i = 0; i < 4; i++)
#pragma unroll
                for (int j = 0; j < 2; j++)
                    acc[i][j] = __builtin_amdgcn_mfma_f32_16x16x32_bf16(av[i], bv[j], acc[i][j], 0, 0, 0);
        }
        __syncthreads();
    }

    // epilogue: C/D layout col(n)=lane&15, row(m)=quad*4+reg  [m89-verified]
#pragma unroll
    for (int i = 0; i < 4; i++) {
        const int m = m0 + i * 16 + quad * 4;
#pragma unroll
        for (int j = 0; j < 2; j++) {
            const int n = n0 + w * 32 + j * 16 + l15;
            float* gp = gout + (size_t)m * FH + n;
#pragma unroll
            for (int r = 0; r < 4; r++) gp[(size_t)r * FH] = acc[i][j][r];
        }
    }
}

// ---------------- K2: cell + head + log_softmax + argmax + output ----------------
// grid 512 blocks (2 batch rows each -> 2 blocks/CU), 256 threads.
__global__ __launch_bounds__(256) void k_head(const float* __restrict__ gpart,
                                              float* __restrict__ cbuf, short* __restrict__ acat,
                                              const float* __restrict__ WihT, const float* __restrict__ bsum,
                                              int* __restrict__ tok,
                                              const float* __restrict__ W1, const float* __restrict__ b1,
                                              const float* __restrict__ W2, const float* __restrict__ b2,
                                              float* __restrict__ outt) {
    const int tid = threadIdx.x;
    const int b0 = blockIdx.x * 2;

    __shared__ float hs[2][512];
    __shared__ float pps[2][2][104];
    __shared__ float ps[2][104];
    __shared__ float red[2][4];
    __shared__ int  redi[2][4];

    const float* __restrict__ g0 = gpart;
    const float* __restrict__ g1 = gpart + (size_t)B_ * FH;

    // ---- phase 1: LSTM cell; writes c (fp32) and next-step A_cat (bf16 hi/hi/lo)
    for (int idx = tid; idx < 2 * H_; idx += 256) {
        const int r = idx >> 9, j = idx & (H_ - 1);
        const int b = b0 + r;
        const int tk = tok[b];
        const float* __restrict__ wr = WihT + (size_t)tk * FH;
        const size_t base = (size_t)b * FH;
        float gi = g0[base + j]        + g1[base + j]        + wr[j]        + bsum[j];
        float gf = g0[base + 512 + j]  + g1[base + 512 + j]  + wr[512 + j]  + bsum[512 + j];
        float gg = g0[base + 1024 + j] + g1[base + 1024 + j] + wr[1024 + j] + bsum[1024 + j];
        float go = g0[base + 1536 + j] + g1[base + 1536 + j] + wr[1536 + j] + bsum[1536 + j];
        float co = cbuf[(size_t)b * H_ + j];
        float cn = sigf(gf) * co + sigf(gi) * tanhf(gg);
        float hn = sigf(go) * tanhf(cn);
        cbuf[(size_t)b * H_ + j] = cn;
        hs[r][j] = hn;
        unsigned short hi = f2bf(hn);
        unsigned short lo = f2bf(hn - bf2f(hi));
        short* ar = acat + (size_t)b * KC;
        ar[j] = (short)hi; ar[512 + j] = (short)hi; ar[1024 + j] = (short)lo;
    }
    __syncthreads();

    // ---- phase 2: p = relu(h @ W1^T + b1), 200 jobs = (gen, k-half), each does both rows
    if (tid < 200) {
        const int gi2 = tid % 100, kq = tid / 100;
        const float4* __restrict__ wrow = (const float4*)(W1 + (size_t)gi2 * H_ + kq * 256);
        float a0 = 0.f, a1 = 0.f;
        for (int k4 = 0; k4 < 64; k4++) {
            float4 wv  = wrow[k4];
            float4 h0 = *(const float4*)&hs[0][kq * 256 + k4 * 4];
            float4 h1 = *(const float4*)&hs[1][kq * 256 + k4 * 4];
            a0 += wv.x * h0.x + wv.y * h0.y + wv.z * h0.z + wv.w * h0.w;
            a1 += wv.x * h1.x + wv.y * h1.y + wv.z * h1.z + wv.w * h1.w;
        }
        pps[kq][0][gi2] = a0; pps[kq][1][gi2] = a1;
    }
    __syncthreads();
    if (tid < 200) {
        const int r = tid / 100, gi2 = tid % 100;
        float v = b1[gi2] + pps[0][r][gi2] + pps[1][r][gi2];
        ps[r][gi2] = v > 0.f ? v : 0.f;
    }
    __syncthreads();

    // ---- phase 3: logits = p @ W2^T + b2; each thread: 4 vocab rows x 2 batch rows
    const int v0 = tid * 4;
    float accv[4][2];  // [vi][r]
#pragma unroll
    for (int vi = 0; vi < 4; vi++) {
        const float bb = b2[v0 + vi];
#pragma unroll
        for (int r = 0; r < 2; r++) accv[vi][r] = bb;
    }
    for (int j4 = 0; j4 < 25; j4++) {
        float4 p0 = *(const float4*)&ps[0][j4 * 4];
        float4 p1 = *(const float4*)&ps[1][j4 * 4];
#pragma unroll
        for (int vi = 0; vi < 4; vi++) {
            float4 wv = *(const float4*)&W2[(size_t)(v0 + vi) * GEN_ + j4 * 4];
            accv[vi][0] += wv.x * p0.x + wv.y * p0.y + wv.z * p0.z + wv.w * p0.w;
            accv[vi][1] += wv.x * p1.x + wv.y * p1.y + wv.z * p1.z + wv.w * p1.w;
        }
    }

    // ---- per-row max + argmax (first-index tie-break, matching np.argmax)
    float lmax[2]; int lidx[2];
#pragma unroll
    for (int r = 0; r < 2; r++) {
        lmax[r] = accv[0][r]; lidx[r] = v0;
#pragma unroll
        for (int vi = 1; vi < 4; vi++)
            if (accv[vi][r] > lmax[r]) { lmax[r] = accv[vi][r]; lidx[r] = v0 + vi; }
    }
#pragma unroll
    for (int off = 32; off; off >>= 1) {
#pragma unroll
        for (int r = 0; r < 2; r++) {
            float ov = __shfl_xor(lmax[r], off);
            int   oi = __shfl_xor(lidx[r], off);
            if (ov > lmax[r] || (ov == lmax[r] && oi < lidx[r])) { lmax[r] = ov; lidx[r] = oi; }
        }
    }
    const int wv2 = tid >> 6, lane = tid & 63;
    if (lane == 0) {
#pragma unroll
        for (int r = 0; r < 2; r++) { red[r][wv2] = lmax[r]; redi[r][wv2] = lidx[r]; }
    }
    __syncthreads();
    float rmax[2]; int ridx[2];
#pragma unroll
    for (int r = 0; r < 2; r++) {
        rmax[r] = red[r][0]; ridx[r] = redi[r][0];
#pragma unroll
        for (int w = 1; w < 4; w++)
            if (red[r][w] > rmax[r] || (red[r][w] == rmax[r] && redi[r][w] < ridx[r])) {
                rmax[r] = red[r][w]; ridx[r] = redi[r][w];
            }
    }
    __syncthreads();  // before reusing red[]

    // ---- sum(exp(x - max))
    float ls[2];
#pragma unroll
    for (int r = 0; r < 2; r++)
        ls[r] = expf(accv[0][r] - rmax[r]) + expf(accv[1][r] - rmax[r]) +
                expf(accv[2][r] - rmax[r]) + expf(accv[3][r] - rmax[r]);
#pragma unroll
    for (int off = 32; off; off >>= 1) {
#pragma unroll
        for (int r = 0; r < 2; r++) ls[r] += __shfl_xor(ls[r], off);
    }
    if (lane == 0) {
#pragma unroll
        for (int r = 0; r < 2; r++) red[r][wv2] = ls[r];
    }
    __syncthreads();
#pragma unroll
    for (int r = 0; r < 2; r++) {
        const float logZ = rmax[r] + logf(red[r][0] + red[r][1] + red[r][2] + red[r][3]);
        float4 o;
        o.x = accv[0][r] - logZ; o.y = accv[1][r] - logZ;
        o.z = accv[2][r] - logZ; o.w = accv[3][r] - logZ;
        *(float4*)&outt[(size_t)(b0 + r) * V_ + v0] = o;
    }
    if (tid == 0) {
        tok[b0 + 0] = ridx[0]; tok[b0 + 1] = ridx[1];
    }
}

// ---------------- host ----------------
extern "C" void kernel_launch(void* const* d_in, const int* in_sizes, int n_in,
                              void* d_out, int out_size, void* d_ws, size_t ws_size,
                              hipStream_t stream) {
    const float* input   = (const float*)d_in[0];
    const float* onehots = (const float*)d_in[1];
    // d_in[2] digits (unused), d_in[3] teacher (==0, free-running path hardcoded)
    const float* Wh  = (const float*)d_in[4];
    const float* bh  = (const float*)d_in[5];
    const float* Wc  = (const float*)d_in[6];
    const float* bc  = (const float*)d_in[7];
    const float* Wih = (const float*)d_in[8];
    const float* Whh = (const float*)d_in[9];
    const float* bih = (const float*)d_in[10];
    const float* bhh = (const float*)d_in[11];
    const float* W1  = (const float*)d_in[12];
    const float* b1  = (const float*)d_in[13];
    const float* W2  = (const float*)d_in[14];
    const float* b2  = (const float*)d_in[15];
    float* out = (float*)d_out;

    char* ws = (char*)d_ws;
    float* gpart = (float*)(ws + OFF_G);
    float* cbuf  = (float*)(ws + OFF_C);
    float* WihT  = (float*)(ws + OFF_WIHT);
    short* acat  = (short*)(ws + OFF_ACAT);
    short* bcat  = (short*)(ws + OFF_BCAT);
    float* bsum  = (float*)(ws + OFF_BSUM);
    int*   tok   = (int*)(ws + OFF_TOK);

    k_init<<<(B_ * H_) / 256, 256, 0, stream>>>(input, Wh, bh, Wc, bc, bih, bhh, cbuf, acat, bsum);
    k_tok0<<<(B_ * V_) / 256, 256, 0, stream>>>(onehots, tok);
    k_transpose<<<(V_ * FH) / 256, 256, 0, stream>>>(Wih, WihT);
    k_prep<<<(FH * H_) / 256, 256, 0, stream>>>(Whh, bcat);

    for (int t = 0; t < T_; t++) {
        k_gates<<<dim3(16, 16, 2), 256, 0, stream>>>(acat, bcat, gpart);
        k_head<<<B_ / 2, 256, 0, stream>>>(gpart, cbuf, acat, WihT, bsum, tok,
                                           W1, b1, W2, b2, out + (size_t)t * B_ * V_);
    }
}

// Round 7
// 4005.347 us; speedup vs baseline: 3.0533x; 1.2839x over previous
//
#include <hip/hip_runtime.h>
#include <math.h>

#define B_   1024
#define T_   64
#define H_   512
#define V_   1024
#define GEN_ 100
#define FH   2048   // 4*H
#define KC   1536   // 3*H concatenated-K for bf16x2 compensated GEMM

// ---------------- workspace layout (bytes) ----------------
static constexpr size_t MB = 1024ull * 1024;
static constexpr size_t OFF_G    = 0;            // 2 * B*FH fp32 split-K partials (16 MB)
static constexpr size_t OFF_C    = 16 * MB;      // B*H fp32 (2 MB)
static constexpr size_t OFF_WIHT = 18 * MB;      // V*FH fp32 (8 MB)
static constexpr size_t OFF_ACAT = 26 * MB;      // B*KC bf16 (3 MB)   [h_hi | h_hi | h_lo]
static constexpr size_t OFF_BCAT = 29 * MB;      // FH*KC bf16 (6 MB)  [W_hi | W_lo | W_hi]
static constexpr size_t OFF_BSUM = 35 * MB;      // FH fp32
static constexpr size_t OFF_TOK  = 35 * MB + 8192;   // B int
static constexpr size_t OFF_H    = 36 * MB;      // B*H fp32 h_t staging (2 MB)

typedef __attribute__((ext_vector_type(8))) short short8v;
typedef __attribute__((ext_vector_type(4))) float f32x4;

__device__ __forceinline__ float sigf(float x) { return 1.0f / (1.0f + expf(-x)); }

__device__ __forceinline__ unsigned short f2bf(float f) {  // RNE fp32 -> bf16
    unsigned int u = __float_as_uint(f);
    return (unsigned short)((u + 0x7FFFu + ((u >> 16) & 1u)) >> 16);
}
__device__ __forceinline__ float bf2f(unsigned short b) {
    return __uint_as_float(((unsigned int)b) << 16);
}

__device__ __forceinline__ void gload16(const void* g, void* l) {
    __builtin_amdgcn_global_load_lds((const __attribute__((address_space(1))) void*)g,
                                     (__attribute__((address_space(3))) void*)l, 16, 0, 0);
}

// ---------------- setup kernels ----------------
__global__ __launch_bounds__(256) void k_init(const float* __restrict__ input,
                                              const float* __restrict__ Wh, const float* __restrict__ bh,
                                              const float* __restrict__ Wc, const float* __restrict__ bc,
                                              const float* __restrict__ bih, const float* __restrict__ bhh,
                                              float* __restrict__ cbuf, short* __restrict__ acat,
                                              float* __restrict__ bsum) {
    int idx = blockIdx.x * 256 + threadIdx.x;  // over B*H
    int b = idx >> 9, j = idx & (H_ - 1);
    float x = input[b];
    float h0 = x * Wh[j] + bh[j];
    cbuf[idx] = x * Wc[j] + bc[j];
    unsigned short hi = f2bf(h0);
    unsigned short lo = f2bf(h0 - bf2f(hi));
    short* ar = acat + (size_t)b * KC;
    ar[j] = (short)hi; ar[512 + j] = (short)hi; ar[1024 + j] = (short)lo;
    if (idx < FH) bsum[idx] = bih[idx] + bhh[idx];
}

__global__ __launch_bounds__(256) void k_tok0(const float* __restrict__ onehots, int* __restrict__ tok) {
    int idx = blockIdx.x * 256 + threadIdx.x;  // over B*V
    int b = idx >> 10, v = idx & (V_ - 1);
    if (onehots[(size_t)b * (T_ * V_) + v] > 0.5f) tok[b] = v;  // exact one-hot: single writer
}

__global__ __launch_bounds__(256) void k_transpose(const float* __restrict__ Wih, float* __restrict__ WihT) {
    int idx = blockIdx.x * 256 + threadIdx.x;  // over V*FH
    int v = idx >> 11, n = idx & (FH - 1);
    WihT[idx] = Wih[(size_t)n * V_ + v];
}

__global__ __launch_bounds__(256) void k_prep(const float* __restrict__ Whh, short* __restrict__ bcat) {
    int idx = blockIdx.x * 256 + threadIdx.x;  // over FH*H
    int n = idx >> 9, k = idx & (H_ - 1);
    float w = Whh[idx];
    unsigned short hi = f2bf(w);
    unsigned short lo = f2bf(w - bf2f(hi));
    short* br = bcat + (size_t)n * KC;
    br[k] = (short)hi; br[512 + k] = (short)lo; br[1024 + k] = (short)hi;
}

// ---------------- K_cell: LSTM cell only (phase 1 of old k_head, verbatim math) ----------------
// grid 512 blocks x 256 threads, 2 batch rows each. Writes cbuf, acat (next gates
// input), and hbuf (fp32 h_t for the out-kernel).
__global__ __launch_bounds__(256) void k_cell(const float* __restrict__ gpart,
                                              float* __restrict__ cbuf, short* __restrict__ acat,
                                              const float* __restrict__ WihT, const float* __restrict__ bsum,
                                              const int* __restrict__ tok,
                                              float* __restrict__ hbuf) {
    const int tid = threadIdx.x;
    const int b0 = blockIdx.x * 2;
    const float* __restrict__ g0 = gpart;
    const float* __restrict__ g1 = gpart + (size_t)B_ * FH;

    for (int idx = tid; idx < 2 * H_; idx += 256) {
        const int r = idx >> 9, j = idx & (H_ - 1);
        const int b = b0 + r;
        const int tk = tok[b];
        const float* __restrict__ wr = WihT + (size_t)tk * FH;
        const size_t base = (size_t)b * FH;
        float gi = g0[base + j]        + g1[base + j]        + wr[j]        + bsum[j];
        float gf = g0[base + 512 + j]  + g1[base + 512 + j]  + wr[512 + j]  + bsum[512 + j];
        float gg = g0[base + 1024 + j] + g1[base + 1024 + j] + wr[1024 + j] + bsum[1024 + j];
        float go = g0[base + 1536 + j] + g1[base + 1536 + j] + wr[1536 + j] + bsum[1536 + j];
        float co = cbuf[(size_t)b * H_ + j];
        float cn = sigf(gf) * co + sigf(gi) * tanhf(gg);
        float hn = sigf(go) * tanhf(cn);
        cbuf[(size_t)b * H_ + j] = cn;
        hbuf[(size_t)b * H_ + j] = hn;
        unsigned short hi = f2bf(hn);
        unsigned short lo = f2bf(hn - bf2f(hi));
        short* ar = acat + (size_t)b * KC;
        ar[j] = (short)hi; ar[512 + j] = (short)hi; ar[1024 + j] = (short)lo;
    }
}

// ---------------- K_fused: [blocks 0..ngates) gates GEMM for t+1] || [rest: head/out for t] ----
// gates role: round-0 k_gates verbatim, 128x128 tile, BK=64, split-K=2, 4 waves.
//   g = blockIdx.x: n0=(g&15)*128, m0=((g>>4)&7)*128, z=g>>7.
// out role: round-0 k_head phases 2-3 verbatim, 4 batch rows, h loaded from hbuf.
// Both roles co-resident across CUs -> MFMA/staging overlaps VALU head compute.
__global__ __launch_bounds__(256) void k_fused(int ngates,
                                               const short* __restrict__ Acat,
                                               const short* __restrict__ Bcat,
                                               float* __restrict__ gpart,
                                               const float* __restrict__ hbuf,
                                               int* __restrict__ tok,
                                               const float* __restrict__ W1, const float* __restrict__ b1,
                                               const float* __restrict__ W2, const float* __restrict__ b2,
                                               float* __restrict__ outt) {
    const int tid = threadIdx.x;
    const int bj = blockIdx.x;

    __shared__ __align__(16) short As[128 * 64];  // 16 KB (gates)
    __shared__ __align__(16) short Bs[128 * 64];  // 16 KB (gates)
    __shared__ float hs[4][512];                  // 8 KB  (out)
    __shared__ float pps[2][4][104];
    __shared__ float ps[4][104];
    __shared__ float red[4][4];
    __shared__ int  redi[4][4];

    if (bj < ngates) {
        // ================= gates GEMM (for step t+1) =================
        const int lane = tid & 63, w = tid >> 6;
        const int n0 = (bj & 15) * 128;
        const int m0 = ((bj >> 4) & 7) * 128;
        const int z  = bj >> 7;
        const int k0 = z * (KC / 2);
        float* __restrict__ gout = gpart + (size_t)z * (B_ * FH);

        f32x4 acc[4][4];
#pragma unroll
        for (int i = 0; i < 4; i++)
#pragma unroll
            for (int j = 0; j < 4; j++) acc[i][j] = (f32x4){0.f, 0.f, 0.f, 0.f};

        const int quad = lane >> 4, l15 = lane & 15;
        const int wm = (w >> 1) * 64, wn = (w & 1) * 64;

        const int srow = lane >> 3;
        const int schunk = (lane & 7) ^ srow;            // XOR chunk swizzle
        const size_t lanoff = (size_t)srow * KC + (size_t)schunk * 8;

        const short* aw = Acat + (size_t)(m0 + w * 32) * KC + k0 + lanoff;
        const short* bw = Bcat + (size_t)(n0 + w * 32) * KC + k0 + lanoff;
        short* lA = &As[w * 32 * 64];
        short* lB = &Bs[w * 32 * 64];

        int raA[4], rxA[4], raB[4], rxB[4];
#pragma unroll
        for (int i = 0; i < 4; i++) {
            int rm = wm + i * 16 + l15; raA[i] = rm * 8; rxA[i] = rm & 7;
            int rn = wn + i * 16 + l15; raB[i] = rn * 8; rxB[i] = rn & 7;
        }

        for (int it = 0; it < (KC / 2) / 64; ++it) {
            const short* ga = aw + it * 64;
            const short* gb = bw + it * 64;
#pragma unroll
            for (int u = 0; u < 4; ++u) {
                gload16(ga + (size_t)(u * 8) * KC, lA + u * 512);
                gload16(gb + (size_t)(u * 8) * KC, lB + u * 512);
            }
            __syncthreads();
#pragma unroll
            for (int kh = 0; kh < 2; ++kh) {
                const int c = kh * 4 + quad;
                short8v av[4], bv[4];
#pragma unroll
                for (int i = 0; i < 4; i++) av[i] = *(const short8v*)&As[(raA[i] + (c ^ rxA[i])) * 8];
#pragma unroll
                for (int j = 0; j < 4; j++) bv[j] = *(const short8v*)&Bs[(raB[j] + (c ^ rxB[j])) * 8];
#pragma unroll
                for (int i = 0; i < 4; i++)
#pragma unroll
                    for (int j = 0; j < 4; j++)
                        acc[i][j] = __builtin_amdgcn_mfma_f32_16x16x32_bf16(av[i], bv[j], acc[i][j], 0, 0, 0);
            }
            __syncthreads();
        }

        // epilogue: C/D layout col(n)=lane&15, row(m)=quad*4+reg  [m89-verified]
#pragma unroll
        for (int i = 0; i < 4; i++) {
            const int m = m0 + wm + i * 16 + quad * 4;
#pragma unroll
            for (int j = 0; j < 4; j++) {
                const int n = n0 + wn + j * 16 + l15;
                float* gp = gout + (size_t)m * FH + n;
#pragma unroll
                for (int r = 0; r < 4; r++) gp[(size_t)r * FH] = acc[i][j][r];
            }
        }
        return;
    }

    // ================= head/out (for step t) =================
    const int b0 = (bj - ngates) * 4;

    // load h rows from hbuf into LDS (same values old phase 1 left in hs)
    for (int idx = tid; idx < 4 * H_; idx += 256)
        hs[idx >> 9][idx & (H_ - 1)] = hbuf[(size_t)(b0 + (idx >> 9)) * H_ + (idx & (H_ - 1))];
    __syncthreads();

    // ---- phase 2: p = relu(h @ W1^T + b1), 200 jobs = (gen, k-half)
    if (tid < 200) {
        const int gi2 = tid % 100, kq = tid / 100;
        const float4* __restrict__ wrow = (const float4*)(W1 + (size_t)gi2 * H_ + kq * 256);
        float a0 = 0.f, a1 = 0.f, a2 = 0.f, a3 = 0.f;
        for (int k4 = 0; k4 < 64; k4++) {
            float4 w  = wrow[k4];
            float4 h0 = *(const float4*)&hs[0][kq * 256 + k4 * 4];
            float4 h1 = *(const float4*)&hs[1][kq * 256 + k4 * 4];
            float4 h2 = *(const float4*)&hs[2][kq * 256 + k4 * 4];
            float4 h3 = *(const float4*)&hs[3][kq * 256 + k4 * 4];
            a0 += w.x * h0.x + w.y * h0.y + w.z * h0.z + w.w * h0.w;
            a1 += w.x * h1.x + w.y * h1.y + w.z * h1.z + w.w * h1.w;
            a2 += w.x * h2.x + w.y * h2.y + w.z * h2.z + w.w * h2.w;
            a3 += w.x * h3.x + w.y * h3.y + w.z * h3.z + w.w * h3.w;
        }
        pps[kq][0][gi2] = a0; pps[kq][1][gi2] = a1;
        pps[kq][2][gi2] = a2; pps[kq][3][gi2] = a3;
    }
    __syncthreads();
    for (int idx = tid; idx < 400; idx += 256) {
        const int r = idx / 100, gi2 = idx % 100;
        float v = b1[gi2] + pps[0][r][gi2] + pps[1][r][gi2];
        ps[r][gi2] = v > 0.f ? v : 0.f;
    }
    __syncthreads();

    // ---- phase 3: logits = p @ W2^T + b2; each thread: 4 vocab rows x all 4 batch rows
    const int v0 = tid * 4;
    float accv[4][4];  // [vi][r]
#pragma unroll
    for (int vi = 0; vi < 4; vi++) {
        const float bb = b2[v0 + vi];
#pragma unroll
        for (int r = 0; r < 4; r++) accv[vi][r] = bb;
    }
    for (int j4 = 0; j4 < 25; j4++) {
        float4 p0 = *(const float4*)&ps[0][j4 * 4];
        float4 p1 = *(const float4*)&ps[1][j4 * 4];
        float4 p2 = *(const float4*)&ps[2][j4 * 4];
        float4 p3 = *(const float4*)&ps[3][j4 * 4];
#pragma unroll
        for (int vi = 0; vi < 4; vi++) {
            float4 w = *(const float4*)&W2[(size_t)(v0 + vi) * GEN_ + j4 * 4];
            accv[vi][0] += w.x * p0.x + w.y * p0.y + w.z * p0.z + w.w * p0.w;
            accv[vi][1] += w.x * p1.x + w.y * p1.y + w.z * p1.z + w.w * p1.w;
            accv[vi][2] += w.x * p2.x + w.y * p2.y + w.z * p2.z + w.w * p2.w;
            accv[vi][3] += w.x * p3.x + w.y * p3.y + w.z * p3.z + w.w * p3.w;
        }
    }

    // ---- per-row max + argmax (first-index tie-break, matching np.argmax)
    float lmax[4]; int lidx[4];
#pragma unroll
    for (int r = 0; r < 4; r++) {
        lmax[r] = accv[0][r]; lidx[r] = v0;
#pragma unroll
        for (int vi = 1; vi < 4; vi++)
            if (accv[vi][r] > lmax[r]) { lmax[r] = accv[vi][r]; lidx[r] = v0 + vi; }
    }
#pragma unroll
    for (int off = 32; off; off >>= 1) {
#pragma unroll
        for (int r = 0; r < 4; r++) {
            float ov = __shfl_xor(lmax[r], off);
            int   oi = __shfl_xor(lidx[r], off);
            if (ov > lmax[r] || (ov == lmax[r] && oi < lidx[r])) { lmax[r] = ov; lidx[r] = oi; }
        }
    }
    const int wv = tid >> 6, lane = tid & 63;
    if (lane == 0) {
#pragma unroll
        for (int r = 0; r < 4; r++) { red[r][wv] = lmax[r]; redi[r][wv] = lidx[r]; }
    }
    __syncthreads();
    float rmax[4]; int ridx[4];
#pragma unroll
    for (int r = 0; r < 4; r++) {
        rmax[r] = red[r][0]; ridx[r] = redi[r][0];
#pragma unroll
        for (int w = 1; w < 4; w++)
            if (red[r][w] > rmax[r] || (red[r][w] == rmax[r] && redi[r][w] < ridx[r])) {
                rmax[r] = red[r][w]; ridx[r] = redi[r][w];
            }
    }
    __syncthreads();  // before reusing red[]

    // ---- sum(exp(x - max))
    float ls[4];
#pragma unroll
    for (int r = 0; r < 4; r++)
        ls[r] = expf(accv[0][r] - rmax[r]) + expf(accv[1][r] - rmax[r]) +
                expf(accv[2][r] - rmax[r]) + expf(accv[3][r] - rmax[r]);
#pragma unroll
    for (int off = 32; off; off >>= 1) {
#pragma unroll
        for (int r = 0; r < 4; r++) ls[r] += __shfl_xor(ls[r], off);
    }
    if (lane == 0) {
#pragma unroll
        for (int r = 0; r < 4; r++) red[r][wv] = ls[r];
    }
    __syncthreads();
#pragma unroll
    for (int r = 0; r < 4; r++) {
        const float logZ = rmax[r] + logf(red[r][0] + red[r][1] + red[r][2] + red[r][3]);
        float4 o;
        o.x = accv[0][r] - logZ; o.y = accv[1][r] - logZ;
        o.z = accv[2][r] - logZ; o.w = accv[3][r] - logZ;
        *(float4*)&outt[(size_t)(b0 + r) * V_ + v0] = o;
    }
    if (tid == 0) {
        tok[b0 + 0] = ridx[0]; tok[b0 + 1] = ridx[1];
        tok[b0 + 2] = ridx[2]; tok[b0 + 3] = ridx[3];
    }
}

// ---------------- host ----------------
extern "C" void kernel_launch(void* const* d_in, const int* in_sizes, int n_in,
                              void* d_out, int out_size, void* d_ws, size_t ws_size,
                              hipStream_t stream) {
    const float* input   = (const float*)d_in[0];
    const float* onehots = (const float*)d_in[1];
    // d_in[2] digits (unused), d_in[3] teacher (==0, free-running path hardcoded)
    const float* Wh  = (const float*)d_in[4];
    const float* bh  = (const float*)d_in[5];
    const float* Wc  = (const float*)d_in[6];
    const float* bc  = (const float*)d_in[7];
    const float* Wih = (const float*)d_in[8];
    const float* Whh = (const float*)d_in[9];
    const float* bih = (const float*)d_in[10];
    const float* bhh = (const float*)d_in[11];
    const float* W1  = (const float*)d_in[12];
    const float* b1  = (const float*)d_in[13];
    const float* W2  = (const float*)d_in[14];
    const float* b2  = (const float*)d_in[15];
    float* out = (float*)d_out;

    char* ws = (char*)d_ws;
    float* gpart = (float*)(ws + OFF_G);
    float* cbuf  = (float*)(ws + OFF_C);
    float* WihT  = (float*)(ws + OFF_WIHT);
    short* acat  = (short*)(ws + OFF_ACAT);
    short* bcat  = (short*)(ws + OFF_BCAT);
    float* bsum  = (float*)(ws + OFF_BSUM);
    int*   tok   = (int*)(ws + OFF_TOK);
    float* hbuf  = (float*)(ws + OFF_H);

    k_init<<<(B_ * H_) / 256, 256, 0, stream>>>(input, Wh, bh, Wc, bc, bih, bhh, cbuf, acat, bsum);
    k_tok0<<<(B_ * V_) / 256, 256, 0, stream>>>(onehots, tok);
    k_transpose<<<(V_ * FH) / 256, 256, 0, stream>>>(Wih, WihT);
    k_prep<<<(FH * H_) / 256, 256, 0, stream>>>(Whh, bcat);

    // pre-gates for t=0 (gates-only launch: ngates == grid)
    k_fused<<<256, 256, 0, stream>>>(256, acat, bcat, gpart, hbuf, tok,
                                     W1, b1, W2, b2, out);

    for (int t = 0; t < T_; t++) {
        k_cell<<<B_ / 2, 256, 0, stream>>>(gpart, cbuf, acat, WihT, bsum, tok, hbuf);
        const int ngates = (t < T_ - 1) ? 256 : 0;  // last step: out-only
        k_fused<<<ngates + 256, 256, 0, stream>>>(ngates, acat, bcat, gpart, hbuf, tok,
                                                  W1, b1, W2, b2, out + (size_t)t * B_ * V_);
    }
}

// Round 8
// 3804.296 us; speedup vs baseline: 3.2147x; 1.0528x over previous
//
#include <hip/hip_runtime.h>
#include <math.h>

#define B_   1024
#define T_   64
#define H_   512
#define V_   1024
#define GEN_ 100
#define FH   2048   // 4*H
#define KC   1536   // 3*H concatenated-K for bf16x2 compensated GEMM

// ---------------- workspace layout (bytes) ----------------
static constexpr size_t MB = 1024ull * 1024;
static constexpr size_t OFF_G    = 0;            // 2 * B*FH fp32 split-K partials (16 MB)
static constexpr size_t OFF_C    = 16 * MB;      // B*H fp32 (2 MB)
static constexpr size_t OFF_WIHT = 18 * MB;      // V*FH fp32 (8 MB)
static constexpr size_t OFF_ACAT = 26 * MB;      // B*KC bf16 (3 MB)   [h_hi | h_hi | h_lo]
static constexpr size_t OFF_BCAT = 29 * MB;      // FH*KC bf16 (6 MB)  [W_hi | W_lo | W_hi]
static constexpr size_t OFF_BSUM = 35 * MB;      // FH fp32
static constexpr size_t OFF_TOK  = 35 * MB + 8192;   // B int
static constexpr size_t OFF_H    = 36 * MB;      // B*H fp32 h_t staging (2 MB)

typedef __attribute__((ext_vector_type(8))) short short8v;
typedef __attribute__((ext_vector_type(4))) float f32x4;

__device__ __forceinline__ float sigf(float x) { return 1.0f / (1.0f + expf(-x)); }

__device__ __forceinline__ unsigned short f2bf(float f) {  // RNE fp32 -> bf16
    unsigned int u = __float_as_uint(f);
    return (unsigned short)((u + 0x7FFFu + ((u >> 16) & 1u)) >> 16);
}
__device__ __forceinline__ float bf2f(unsigned short b) {
    return __uint_as_float(((unsigned int)b) << 16);
}

__device__ __forceinline__ void gload16(const void* g, void* l) {
    __builtin_amdgcn_global_load_lds((const __attribute__((address_space(1))) void*)g,
                                     (__attribute__((address_space(3))) void*)l, 16, 0, 0);
}

// ---------------- setup kernels ----------------
__global__ __launch_bounds__(256) void k_init(const float* __restrict__ input,
                                              const float* __restrict__ Wh, const float* __restrict__ bh,
                                              const float* __restrict__ Wc, const float* __restrict__ bc,
                                              const float* __restrict__ bih, const float* __restrict__ bhh,
                                              float* __restrict__ cbuf, short* __restrict__ acat,
                                              float* __restrict__ bsum) {
    int idx = blockIdx.x * 256 + threadIdx.x;  // over B*H
    int b = idx >> 9, j = idx & (H_ - 1);
    float x = input[b];
    float h0 = x * Wh[j] + bh[j];
    cbuf[idx] = x * Wc[j] + bc[j];
    unsigned short hi = f2bf(h0);
    unsigned short lo = f2bf(h0 - bf2f(hi));
    short* ar = acat + (size_t)b * KC;
    ar[j] = (short)hi; ar[512 + j] = (short)hi; ar[1024 + j] = (short)lo;
    if (idx < FH) bsum[idx] = bih[idx] + bhh[idx];
}

__global__ __launch_bounds__(256) void k_tok0(const float* __restrict__ onehots, int* __restrict__ tok) {
    int idx = blockIdx.x * 256 + threadIdx.x;  // over B*V
    int b = idx >> 10, v = idx & (V_ - 1);
    if (onehots[(size_t)b * (T_ * V_) + v] > 0.5f) tok[b] = v;  // exact one-hot: single writer
}

__global__ __launch_bounds__(256) void k_transpose(const float* __restrict__ Wih, float* __restrict__ WihT) {
    int idx = blockIdx.x * 256 + threadIdx.x;  // over V*FH
    int v = idx >> 11, n = idx & (FH - 1);
    WihT[idx] = Wih[(size_t)n * V_ + v];
}

__global__ __launch_bounds__(256) void k_prep(const float* __restrict__ Whh, short* __restrict__ bcat) {
    int idx = blockIdx.x * 256 + threadIdx.x;  // over FH*H
    int n = idx >> 9, k = idx & (H_ - 1);
    float w = Whh[idx];
    unsigned short hi = f2bf(w);
    unsigned short lo = f2bf(w - bf2f(hi));
    short* br = bcat + (size_t)n * KC;
    br[k] = (short)hi; br[512 + k] = (short)lo; br[1024 + k] = (short)hi;
}

// ---------------- K_cell: LSTM cell (float4-vectorized; per-element math verbatim) ----------------
// grid 512 blocks x 256 threads, 2 batch rows each; each thread owns one j-quad.
__global__ __launch_bounds__(256) void k_cell(const float* __restrict__ gpart,
                                              float* __restrict__ cbuf, short* __restrict__ acat,
                                              const float* __restrict__ WihT, const float* __restrict__ bsum,
                                              const int* __restrict__ tok,
                                              float* __restrict__ hbuf) {
    const int tid = threadIdx.x;
    const int b = blockIdx.x * 2 + (tid >> 7);
    const int j = (tid & 127) << 2;            // 0,4,...,508
    const int tk = tok[b];
    const float* __restrict__ wr = WihT + (size_t)tk * FH;
    const float* __restrict__ g0 = gpart;
    const float* __restrict__ g1 = gpart + (size_t)B_ * FH;
    const size_t base = (size_t)b * FH;

    float4 g4[4];
#pragma unroll
    for (int gi_ = 0; gi_ < 4; ++gi_) {
        const int off = gi_ * 512 + j;
        float4 a0 = *(const float4*)&g0[base + off];
        float4 a1 = *(const float4*)&g1[base + off];
        float4 wv = *(const float4*)&wr[off];
        float4 bs = *(const float4*)&bsum[off];
        // per-element order identical to scalar version: g0 + g1 + wr + bsum
        g4[gi_].x = a0.x + a1.x + wv.x + bs.x;
        g4[gi_].y = a0.y + a1.y + wv.y + bs.y;
        g4[gi_].z = a0.z + a1.z + wv.z + bs.z;
        g4[gi_].w = a0.w + a1.w + wv.w + bs.w;
    }
    float4 co = *(const float4*)&cbuf[(size_t)b * H_ + j];
    float cn[4], hn[4];
    const float* gi_p = (const float*)&g4[0];
    const float* gf_p = (const float*)&g4[1];
    const float* gg_p = (const float*)&g4[2];
    const float* go_p = (const float*)&g4[3];
    const float* co_p = (const float*)&co;
#pragma unroll
    for (int e = 0; e < 4; ++e) {
        cn[e] = sigf(gf_p[e]) * co_p[e] + sigf(gi_p[e]) * tanhf(gg_p[e]);
        hn[e] = sigf(go_p[e]) * tanhf(cn[e]);
    }
    *(float4*)&cbuf[(size_t)b * H_ + j] = make_float4(cn[0], cn[1], cn[2], cn[3]);
    *(float4*)&hbuf[(size_t)b * H_ + j] = make_float4(hn[0], hn[1], hn[2], hn[3]);
    unsigned long long hh = 0ull, ll = 0ull;
#pragma unroll
    for (int e = 0; e < 4; ++e) {
        unsigned short hi = f2bf(hn[e]);
        unsigned short lo = f2bf(hn[e] - bf2f(hi));
        hh |= (unsigned long long)hi << (16 * e);
        ll |= (unsigned long long)lo << (16 * e);
    }
    short* ar = acat + (size_t)b * KC;
    *(unsigned long long*)&ar[j]        = hh;
    *(unsigned long long*)&ar[512 + j]  = hh;
    *(unsigned long long*)&ar[1024 + j] = ll;
}

// ---------------- K_fused: [blocks 0..ngates) gates GEMM for t+1] || [rest: head/out for t] ----
// gates role: 128x128 tile, BK=64, split-K=2, 4 waves, DOUBLE-BUFFERED staging.
// out role: head phases 2-3 verbatim (unrolled k-loops), 4 batch rows from hbuf.
// LDS: union of the two roles (roles are block-uniform) -> 64 KB, 2 blocks/CU.
__global__ __launch_bounds__(256) void k_fused(int ngates,
                                               const short* __restrict__ Acat,
                                               const short* __restrict__ Bcat,
                                               float* __restrict__ gpart,
                                               const float* __restrict__ hbuf,
                                               int* __restrict__ tok,
                                               const float* __restrict__ W1, const float* __restrict__ b1,
                                               const float* __restrict__ W2, const float* __restrict__ b2,
                                               float* __restrict__ outt) {
    const int tid = threadIdx.x;
    const int bj = blockIdx.x;

    union SMem {
        struct { short As[2][128 * 64]; short Bs[2][128 * 64]; } g;   // 64 KB
        struct { float hs[4][512]; float pps[2][4][104]; float ps[4][104];
                 float red[4][4]; int redi[4][4]; } h;                // ~13 KB
    };
    __shared__ __align__(16) SMem sm;

    if (bj < ngates) {
        // ================= gates GEMM (for step t+1), double-buffered =================
        const int lane = tid & 63, w = tid >> 6;
        const int n0 = (bj & 15) * 128;
        const int m0 = ((bj >> 4) & 7) * 128;
        const int z  = bj >> 7;
        const int k0 = z * (KC / 2);
        float* __restrict__ gout = gpart + (size_t)z * (B_ * FH);

        f32x4 acc[4][4];
#pragma unroll
        for (int i = 0; i < 4; i++)
#pragma unroll
            for (int j = 0; j < 4; j++) acc[i][j] = (f32x4){0.f, 0.f, 0.f, 0.f};

        const int quad = lane >> 4, l15 = lane & 15;
        const int wm = (w >> 1) * 64, wn = (w & 1) * 64;

        const int srow = lane >> 3;
        const int schunk = (lane & 7) ^ srow;            // XOR chunk swizzle
        const size_t lanoff = (size_t)srow * KC + (size_t)schunk * 8;

        const short* aw = Acat + (size_t)(m0 + w * 32) * KC + k0 + lanoff;
        const short* bw = Bcat + (size_t)(n0 + w * 32) * KC + k0 + lanoff;

        int raA[4], rxA[4], raB[4], rxB[4];
#pragma unroll
        for (int i = 0; i < 4; i++) {
            int rm = wm + i * 16 + l15; raA[i] = rm * 8; rxA[i] = rm & 7;
            int rn = wn + i * 16 + l15; raB[i] = rn * 8; rxB[i] = rn & 7;
        }

        // prologue: stage k-iter 0 into buf0
#pragma unroll
        for (int u = 0; u < 4; ++u) {
            gload16(aw + (size_t)(u * 8) * KC, &sm.g.As[0][w * 2048] + u * 512);
            gload16(bw + (size_t)(u * 8) * KC, &sm.g.Bs[0][w * 2048] + u * 512);
        }
        __syncthreads();
#pragma unroll
        for (int it = 0; it < 12; ++it) {
            if (it < 11) {  // issue next-iter stage into the other buffer
                const int nb = (it + 1) & 1;
                const short* ga = aw + (it + 1) * 64;
                const short* gb = bw + (it + 1) * 64;
#pragma unroll
                for (int u = 0; u < 4; ++u) {
                    gload16(ga + (size_t)(u * 8) * KC, &sm.g.As[nb][w * 2048] + u * 512);
                    gload16(gb + (size_t)(u * 8) * KC, &sm.g.Bs[nb][w * 2048] + u * 512);
                }
            }
            const short* Ab = &sm.g.As[it & 1][0];
            const short* Bb = &sm.g.Bs[it & 1][0];
#pragma unroll
            for (int kh = 0; kh < 2; ++kh) {
                const int c = kh * 4 + quad;
                short8v av[4], bv[4];
#pragma unroll
                for (int i = 0; i < 4; i++) av[i] = *(const short8v*)&Ab[(raA[i] + (c ^ rxA[i])) * 8];
#pragma unroll
                for (int j = 0; j < 4; j++) bv[j] = *(const short8v*)&Bb[(raB[j] + (c ^ rxB[j])) * 8];
#pragma unroll
                for (int i = 0; i < 4; i++)
#pragma unroll
                    for (int j = 0; j < 4; j++)
                        acc[i][j] = __builtin_amdgcn_mfma_f32_16x16x32_bf16(av[i], bv[j], acc[i][j], 0, 0, 0);
            }
            __syncthreads();  // drains this iter's stage (vmcnt) + guards buffer reuse
        }

        // epilogue: C/D layout col(n)=lane&15, row(m)=quad*4+reg  [m89-verified]
#pragma unroll
        for (int i = 0; i < 4; i++) {
            const int m = m0 + wm + i * 16 + quad * 4;
#pragma unroll
            for (int j = 0; j < 4; j++) {
                const int n = n0 + wn + j * 16 + l15;
                float* gp = gout + (size_t)m * FH + n;
#pragma unroll
                for (int r = 0; r < 4; r++) gp[(size_t)r * FH] = acc[i][j][r];
            }
        }
        return;
    }

    // ================= head/out (for step t) =================
    const int b0 = (bj - ngates) * 4;

    // load h rows from hbuf into LDS (float4)
    for (int idx = tid; idx < 512; idx += 256) {
        const int r = idx >> 7, jq = (idx & 127) << 2;
        *(float4*)&sm.h.hs[r][jq] = *(const float4*)&hbuf[(size_t)(b0 + r) * H_ + jq];
    }
    __syncthreads();

    // ---- phase 2: p = relu(h @ W1^T + b1), 200 jobs = (gen, k-half)
    if (tid < 200) {
        const int gi2 = tid % 100, kq = tid / 100;
        const float4* __restrict__ wrow = (const float4*)(W1 + (size_t)gi2 * H_ + kq * 256);
        float a0 = 0.f, a1 = 0.f, a2 = 0.f, a3 = 0.f;
#pragma unroll 4
        for (int k4 = 0; k4 < 64; k4++) {
            float4 w  = wrow[k4];
            float4 h0 = *(const float4*)&sm.h.hs[0][kq * 256 + k4 * 4];
            float4 h1 = *(const float4*)&sm.h.hs[1][kq * 256 + k4 * 4];
            float4 h2 = *(const float4*)&sm.h.hs[2][kq * 256 + k4 * 4];
            float4 h3 = *(const float4*)&sm.h.hs[3][kq * 256 + k4 * 4];
            a0 += w.x * h0.x + w.y * h0.y + w.z * h0.z + w.w * h0.w;
            a1 += w.x * h1.x + w.y * h1.y + w.z * h1.z + w.w * h1.w;
            a2 += w.x * h2.x + w.y * h2.y + w.z * h2.z + w.w * h2.w;
            a3 += w.x * h3.x + w.y * h3.y + w.z * h3.z + w.w * h3.w;
        }
        sm.h.pps[kq][0][gi2] = a0; sm.h.pps[kq][1][gi2] = a1;
        sm.h.pps[kq][2][gi2] = a2; sm.h.pps[kq][3][gi2] = a3;
    }
    __syncthreads();
    for (int idx = tid; idx < 400; idx += 256) {
        const int r = idx / 100, gi2 = idx % 100;
        float v = b1[gi2] + sm.h.pps[0][r][gi2] + sm.h.pps[1][r][gi2];
        sm.h.ps[r][gi2] = v > 0.f ? v : 0.f;
    }
    __syncthreads();

    // ---- phase 3: logits = p @ W2^T + b2; each thread: 4 vocab rows x all 4 batch rows
    const int v0 = tid * 4;
    float accv[4][4];  // [vi][r]
#pragma unroll
    for (int vi = 0; vi < 4; vi++) {
        const float bb = b2[v0 + vi];
#pragma unroll
        for (int r = 0; r < 4; r++) accv[vi][r] = bb;
    }
#pragma unroll 5
    for (int j4 = 0; j4 < 25; j4++) {
        float4 p0 = *(const float4*)&sm.h.ps[0][j4 * 4];
        float4 p1 = *(const float4*)&sm.h.ps[1][j4 * 4];
        float4 p2 = *(const float4*)&sm.h.ps[2][j4 * 4];
        float4 p3 = *(const float4*)&sm.h.ps[3][j4 * 4];
#pragma unroll
        for (int vi = 0; vi < 4; vi++) {
            float4 w = *(const float4*)&W2[(size_t)(v0 + vi) * GEN_ + j4 * 4];
            accv[vi][0] += w.x * p0.x + w.y * p0.y + w.z * p0.z + w.w * p0.w;
            accv[vi][1] += w.x * p1.x + w.y * p1.y + w.z * p1.z + w.w * p1.w;
            accv[vi][2] += w.x * p2.x + w.y * p2.y + w.z * p2.z + w.w * p2.w;
            accv[vi][3] += w.x * p3.x + w.y * p3.y + w.z * p3.z + w.w * p3.w;
        }
    }

    // ---- per-row max + argmax (first-index tie-break, matching np.argmax)
    float lmax[4]; int lidx[4];
#pragma unroll
    for (int r = 0; r < 4; r++) {
        lmax[r] = accv[0][r]; lidx[r] = v0;
#pragma unroll
        for (int vi = 1; vi < 4; vi++)
            if (accv[vi][r] > lmax[r]) { lmax[r] = accv[vi][r]; lidx[r] = v0 + vi; }
    }
#pragma unroll
    for (int off = 32; off; off >>= 1) {
#pragma unroll
        for (int r = 0; r < 4; r++) {
            float ov = __shfl_xor(lmax[r], off);
            int   oi = __shfl_xor(lidx[r], off);
            if (ov > lmax[r] || (ov == lmax[r] && oi < lidx[r])) { lmax[r] = ov; lidx[r] = oi; }
        }
    }
    const int wv = tid >> 6, lane = tid & 63;
    if (lane == 0) {
#pragma unroll
        for (int r = 0; r < 4; r++) { sm.h.red[r][wv] = lmax[r]; sm.h.redi[r][wv] = lidx[r]; }
    }
    __syncthreads();
    float rmax[4]; int ridx[4];
#pragma unroll
    for (int r = 0; r < 4; r++) {
        rmax[r] = sm.h.red[r][0]; ridx[r] = sm.h.redi[r][0];
#pragma unroll
        for (int w = 1; w < 4; w++)
            if (sm.h.red[r][w] > rmax[r] || (sm.h.red[r][w] == rmax[r] && sm.h.redi[r][w] < ridx[r])) {
                rmax[r] = sm.h.red[r][w]; ridx[r] = sm.h.redi[r][w];
            }
    }
    __syncthreads();  // before reusing red[]

    // ---- sum(exp(x - max))
    float ls[4];
#pragma unroll
    for (int r = 0; r < 4; r++)
        ls[r] = expf(accv[0][r] - rmax[r]) + expf(accv[1][r] - rmax[r]) +
                expf(accv[2][r] - rmax[r]) + expf(accv[3][r] - rmax[r]);
#pragma unroll
    for (int off = 32; off; off >>= 1) {
#pragma unroll
        for (int r = 0; r < 4; r++) ls[r] += __shfl_xor(ls[r], off);
    }
    if (lane == 0) {
#pragma unroll
        for (int r = 0; r < 4; r++) sm.h.red[r][wv] = ls[r];
    }
    __syncthreads();
#pragma unroll
    for (int r = 0; r < 4; r++) {
        const float logZ = rmax[r] + logf(sm.h.red[r][0] + sm.h.red[r][1] + sm.h.red[r][2] + sm.h.red[r][3]);
        float4 o;
        o.x = accv[0][r] - logZ; o.y = accv[1][r] - logZ;
        o.z = accv[2][r] - logZ; o.w = accv[3][r] - logZ;
        *(float4*)&outt[(size_t)(b0 + r) * V_ + v0] = o;
    }
    if (tid == 0) {
        tok[b0 + 0] = ridx[0]; tok[b0 + 1] = ridx[1];
        tok[b0 + 2] = ridx[2]; tok[b0 + 3] = ridx[3];
    }
}

// ---------------- host ----------------
extern "C" void kernel_launch(void* const* d_in, const int* in_sizes, int n_in,
                              void* d_out, int out_size, void* d_ws, size_t ws_size,
                              hipStream_t stream) {
    const float* input   = (const float*)d_in[0];
    const float* onehots = (const float*)d_in[1];
    // d_in[2] digits (unused), d_in[3] teacher (==0, free-running path hardcoded)
    const float* Wh  = (const float*)d_in[4];
    const float* bh  = (const float*)d_in[5];
    const float* Wc  = (const float*)d_in[6];
    const float* bc  = (const float*)d_in[7];
    const float* Wih = (const float*)d_in[8];
    const float* Whh = (const float*)d_in[9];
    const float* bih = (const float*)d_in[10];
    const float* bhh = (const float*)d_in[11];
    const float* W1  = (const float*)d_in[12];
    const float* b1  = (const float*)d_in[13];
    const float* W2  = (const float*)d_in[14];
    const float* b2  = (const float*)d_in[15];
    float* out = (float*)d_out;

    char* ws = (char*)d_ws;
    float* gpart = (float*)(ws + OFF_G);
    float* cbuf  = (float*)(ws + OFF_C);
    float* WihT  = (float*)(ws + OFF_WIHT);
    short* acat  = (short*)(ws + OFF_ACAT);
    short* bcat  = (short*)(ws + OFF_BCAT);
    float* bsum  = (float*)(ws + OFF_BSUM);
    int*   tok   = (int*)(ws + OFF_TOK);
    float* hbuf  = (float*)(ws + OFF_H);

    k_init<<<(B_ * H_) / 256, 256, 0, stream>>>(input, Wh, bh, Wc, bc, bih, bhh, cbuf, acat, bsum);
    k_tok0<<<(B_ * V_) / 256, 256, 0, stream>>>(onehots, tok);
    k_transpose<<<(V_ * FH) / 256, 256, 0, stream>>>(Wih, WihT);
    k_prep<<<(FH * H_) / 256, 256, 0, stream>>>(Whh, bcat);

    // pre-gates for t=0 (gates-only launch: ngates == grid)
    k_fused<<<256, 256, 0, stream>>>(256, acat, bcat, gpart, hbuf, tok,
                                     W1, b1, W2, b2, out);

    for (int t = 0; t < T_; t++) {
        k_cell<<<B_ / 2, 256, 0, stream>>>(gpart, cbuf, acat, WihT, bsum, tok, hbuf);
        const int ngates = (t < T_ - 1) ? 256 : 0;  // last step: out-only
        k_fused<<<ngates + 256, 256, 0, stream>>>(ngates, acat, bcat, gpart, hbuf, tok,
                                                  W1, b1, W2, b2, out + (size_t)t * B_ * V_);
    }
}

// Round 9
// 3792.570 us; speedup vs baseline: 3.2246x; 1.0031x over previous
//
#include <hip/hip_runtime.h>
#include <math.h>

#define B_   1024
#define T_   64
#define H_   512
#define V_   1024
#define GEN_ 100
#define FH   2048   // 4*H
#define KC   1536   // 3*H concatenated-K for bf16x2 compensated GEMM

// ---------------- workspace layout (bytes) ----------------
static constexpr size_t MB = 1024ull * 1024;
static constexpr size_t OFF_G    = 0;            // B*FH fp32 gates (8 MB, no split-K)
static constexpr size_t OFF_C    = 16 * MB;      // B*H fp32 (2 MB)
static constexpr size_t OFF_WIHT = 18 * MB;      // V*FH fp32 (8 MB)
static constexpr size_t OFF_ACAT = 26 * MB;      // B*KC bf16 (3 MB)   [h_hi | h_hi | h_lo]
static constexpr size_t OFF_BCAT = 29 * MB;      // FH*KC bf16 (6 MB)  [W_hi | W_lo | W_hi]
static constexpr size_t OFF_BSUM = 35 * MB;      // FH fp32
static constexpr size_t OFF_TOK  = 35 * MB + 8192;   // B int
static constexpr size_t OFF_H    = 36 * MB;      // B*H fp32 h_t staging (2 MB)

typedef __attribute__((ext_vector_type(8))) short short8v;
typedef __attribute__((ext_vector_type(4))) float f32x4;

__device__ __forceinline__ float sigf(float x) { return 1.0f / (1.0f + expf(-x)); }

__device__ __forceinline__ unsigned short f2bf(float f) {  // RNE fp32 -> bf16
    unsigned int u = __float_as_uint(f);
    return (unsigned short)((u + 0x7FFFu + ((u >> 16) & 1u)) >> 16);
}
__device__ __forceinline__ float bf2f(unsigned short b) {
    return __uint_as_float(((unsigned int)b) << 16);
}

__device__ __forceinline__ void gload16(const void* g, void* l) {
    __builtin_amdgcn_global_load_lds((const __attribute__((address_space(1))) void*)g,
                                     (__attribute__((address_space(3))) void*)l, 16, 0, 0);
}

// ---------------- setup kernels ----------------
__global__ __launch_bounds__(256) void k_init(const float* __restrict__ input,
                                              const float* __restrict__ Wh, const float* __restrict__ bh,
                                              const float* __restrict__ Wc, const float* __restrict__ bc,
                                              const float* __restrict__ bih, const float* __restrict__ bhh,
                                              float* __restrict__ cbuf, short* __restrict__ acat,
                                              float* __restrict__ bsum) {
    int idx = blockIdx.x * 256 + threadIdx.x;  // over B*H
    int b = idx >> 9, j = idx & (H_ - 1);
    float x = input[b];
    float h0 = x * Wh[j] + bh[j];
    cbuf[idx] = x * Wc[j] + bc[j];
    unsigned short hi = f2bf(h0);
    unsigned short lo = f2bf(h0 - bf2f(hi));
    short* ar = acat + (size_t)b * KC;
    ar[j] = (short)hi; ar[512 + j] = (short)hi; ar[1024 + j] = (short)lo;
    if (idx < FH) bsum[idx] = bih[idx] + bhh[idx];
}

__global__ __launch_bounds__(256) void k_tok0(const float* __restrict__ onehots, int* __restrict__ tok) {
    int idx = blockIdx.x * 256 + threadIdx.x;  // over B*V
    int b = idx >> 10, v = idx & (V_ - 1);
    if (onehots[(size_t)b * (T_ * V_) + v] > 0.5f) tok[b] = v;  // exact one-hot: single writer
}

__global__ __launch_bounds__(256) void k_transpose(const float* __restrict__ Wih, float* __restrict__ WihT) {
    int idx = blockIdx.x * 256 + threadIdx.x;  // over V*FH
    int v = idx >> 11, n = idx & (FH - 1);
    WihT[idx] = Wih[(size_t)n * V_ + v];
}

__global__ __launch_bounds__(256) void k_prep(const float* __restrict__ Whh, short* __restrict__ bcat) {
    int idx = blockIdx.x * 256 + threadIdx.x;  // over FH*H
    int n = idx >> 9, k = idx & (H_ - 1);
    float w = Whh[idx];
    unsigned short hi = f2bf(w);
    unsigned short lo = f2bf(w - bf2f(hi));
    short* br = bcat + (size_t)n * KC;
    br[k] = (short)hi; br[512 + k] = (short)lo; br[1024 + k] = (short)hi;
}

// ---------------- K_cell: LSTM cell (float4-vectorized, single gates buffer) ----------------
// grid 512 blocks x 256 threads, 2 batch rows each; each thread owns one j-quad.
__global__ __launch_bounds__(256) void k_cell(const float* __restrict__ gbuf,
                                              float* __restrict__ cbuf, short* __restrict__ acat,
                                              const float* __restrict__ WihT, const float* __restrict__ bsum,
                                              const int* __restrict__ tok,
                                              float* __restrict__ hbuf) {
    const int tid = threadIdx.x;
    const int b = blockIdx.x * 2 + (tid >> 7);
    const int j = (tid & 127) << 2;            // 0,4,...,508
    const int tk = tok[b];
    const float* __restrict__ wr = WihT + (size_t)tk * FH;
    const size_t base = (size_t)b * FH;

    float4 g4[4];
#pragma unroll
    for (int gi_ = 0; gi_ < 4; ++gi_) {
        const int off = gi_ * 512 + j;
        float4 a0 = *(const float4*)&gbuf[base + off];
        float4 wv = *(const float4*)&wr[off];
        float4 bs = *(const float4*)&bsum[off];
        g4[gi_].x = a0.x + wv.x + bs.x;
        g4[gi_].y = a0.y + wv.y + bs.y;
        g4[gi_].z = a0.z + wv.z + bs.z;
        g4[gi_].w = a0.w + wv.w + bs.w;
    }
    float4 co = *(const float4*)&cbuf[(size_t)b * H_ + j];
    float cn[4], hn[4];
    const float* gi_p = (const float*)&g4[0];
    const float* gf_p = (const float*)&g4[1];
    const float* gg_p = (const float*)&g4[2];
    const float* go_p = (const float*)&g4[3];
    const float* co_p = (const float*)&co;
#pragma unroll
    for (int e = 0; e < 4; ++e) {
        cn[e] = sigf(gf_p[e]) * co_p[e] + sigf(gi_p[e]) * tanhf(gg_p[e]);
        hn[e] = sigf(go_p[e]) * tanhf(cn[e]);
    }
    *(float4*)&cbuf[(size_t)b * H_ + j] = make_float4(cn[0], cn[1], cn[2], cn[3]);
    *(float4*)&hbuf[(size_t)b * H_ + j] = make_float4(hn[0], hn[1], hn[2], hn[3]);
    unsigned long long hh = 0ull, ll = 0ull;
#pragma unroll
    for (int e = 0; e < 4; ++e) {
        unsigned short hi = f2bf(hn[e]);
        unsigned short lo = f2bf(hn[e] - bf2f(hi));
        hh |= (unsigned long long)hi << (16 * e);
        ll |= (unsigned long long)lo << (16 * e);
    }
    short* ar = acat + (size_t)b * KC;
    *(unsigned long long*)&ar[j]        = hh;
    *(unsigned long long*)&ar[512 + j]  = hh;
    *(unsigned long long*)&ar[1024 + j] = ll;
}

// ---------------- K_fused: [blocks 0..ngates) gates GEMM for t+1] || [rest: head/out for t] ----
// gates role: 128x128 tile, FULL K=1536 (24 dbuf iters), 128 blocks, 4 waves.
// out role: head phases 2-3 (unrolled k-loops), 4 batch rows from hbuf.
// LDS: union of the two roles (roles are block-uniform) -> 64 KB, 2 blocks/CU.
__global__ __launch_bounds__(256) void k_fused(int ngates,
                                               const short* __restrict__ Acat,
                                               const short* __restrict__ Bcat,
                                               float* __restrict__ gbuf,
                                               const float* __restrict__ hbuf,
                                               int* __restrict__ tok,
                                               const float* __restrict__ W1, const float* __restrict__ b1,
                                               const float* __restrict__ W2, const float* __restrict__ b2,
                                               float* __restrict__ outt) {
    const int tid = threadIdx.x;
    const int bj = blockIdx.x;

    union SMem {
        struct { short As[2][128 * 64]; short Bs[2][128 * 64]; } g;   // 64 KB
        struct { float hs[4][512]; float pps[2][4][104]; float ps[4][104];
                 float red[4][4]; int redi[4][4]; } h;                // ~13 KB
    };
    __shared__ __align__(16) SMem sm;

    if (bj < ngates) {
        // ================= gates GEMM (for step t+1), full-K, double-buffered =================
        const int lane = tid & 63, w = tid >> 6;
        const int n0 = (bj & 15) * 128;
        const int m0 = (bj >> 4) * 128;

        f32x4 acc[4][4];
#pragma unroll
        for (int i = 0; i < 4; i++)
#pragma unroll
            for (int j = 0; j < 4; j++) acc[i][j] = (f32x4){0.f, 0.f, 0.f, 0.f};

        const int quad = lane >> 4, l15 = lane & 15;
        const int wm = (w >> 1) * 64, wn = (w & 1) * 64;

        const int srow = lane >> 3;
        const int schunk = (lane & 7) ^ srow;            // XOR chunk swizzle
        const size_t lanoff = (size_t)srow * KC + (size_t)schunk * 8;

        const short* aw = Acat + (size_t)(m0 + w * 32) * KC + lanoff;
        const short* bw = Bcat + (size_t)(n0 + w * 32) * KC + lanoff;

        int raA[4], rxA[4], raB[4], rxB[4];
#pragma unroll
        for (int i = 0; i < 4; i++) {
            int rm = wm + i * 16 + l15; raA[i] = rm * 8; rxA[i] = rm & 7;
            int rn = wn + i * 16 + l15; raB[i] = rn * 8; rxB[i] = rn & 7;
        }

        // prologue: stage k-iter 0 into buf0
#pragma unroll
        for (int u = 0; u < 4; ++u) {
            gload16(aw + (size_t)(u * 8) * KC, &sm.g.As[0][w * 2048] + u * 512);
            gload16(bw + (size_t)(u * 8) * KC, &sm.g.Bs[0][w * 2048] + u * 512);
        }
        __syncthreads();
#pragma unroll 2
        for (int it = 0; it < 24; ++it) {     // unroll 2 keeps (it&1) static
            if (it < 23) {  // issue next-iter stage into the other buffer
                const int nb = (it + 1) & 1;
                const short* ga = aw + (it + 1) * 64;
                const short* gb = bw + (it + 1) * 64;
#pragma unroll
                for (int u = 0; u < 4; ++u) {
                    gload16(ga + (size_t)(u * 8) * KC, &sm.g.As[nb][w * 2048] + u * 512);
                    gload16(gb + (size_t)(u * 8) * KC, &sm.g.Bs[nb][w * 2048] + u * 512);
                }
            }
            const short* Ab = &sm.g.As[it & 1][0];
            const short* Bb = &sm.g.Bs[it & 1][0];
#pragma unroll
            for (int kh = 0; kh < 2; ++kh) {
                const int c = kh * 4 + quad;
                short8v av[4], bv[4];
#pragma unroll
                for (int i = 0; i < 4; i++) av[i] = *(const short8v*)&Ab[(raA[i] + (c ^ rxA[i])) * 8];
#pragma unroll
                for (int j = 0; j < 4; j++) bv[j] = *(const short8v*)&Bb[(raB[j] + (c ^ rxB[j])) * 8];
#pragma unroll
                for (int i = 0; i < 4; i++)
#pragma unroll
                    for (int j = 0; j < 4; j++)
                        acc[i][j] = __builtin_amdgcn_mfma_f32_16x16x32_bf16(av[i], bv[j], acc[i][j], 0, 0, 0);
            }
            __syncthreads();  // drains this iter's stage (vmcnt) + guards buffer reuse
        }

        // epilogue: C/D layout col(n)=lane&15, row(m)=quad*4+reg  [m89-verified]
#pragma unroll
        for (int i = 0; i < 4; i++) {
            const int m = m0 + wm + i * 16 + quad * 4;
#pragma unroll
            for (int j = 0; j < 4; j++) {
                const int n = n0 + wn + j * 16 + l15;
                float* gp = gbuf + (size_t)m * FH + n;
#pragma unroll
                for (int r = 0; r < 4; r++) gp[(size_t)r * FH] = acc[i][j][r];
            }
        }
        return;
    }

    // ================= head/out (for step t) =================
    const int b0 = (bj - ngates) * 4;

    // load h rows from hbuf into LDS (float4)
    for (int idx = tid; idx < 512; idx += 256) {
        const int r = idx >> 7, jq = (idx & 127) << 2;
        *(float4*)&sm.h.hs[r][jq] = *(const float4*)&hbuf[(size_t)(b0 + r) * H_ + jq];
    }
    __syncthreads();

    // ---- phase 2: p = relu(h @ W1^T + b1), 200 jobs = (gen, k-half)
    if (tid < 200) {
        const int gi2 = tid % 100, kq = tid / 100;
        const float4* __restrict__ wrow = (const float4*)(W1 + (size_t)gi2 * H_ + kq * 256);
        float a0 = 0.f, a1 = 0.f, a2 = 0.f, a3 = 0.f;
#pragma unroll 4
        for (int k4 = 0; k4 < 64; k4++) {
            float4 w  = wrow[k4];
            float4 h0 = *(const float4*)&sm.h.hs[0][kq * 256 + k4 * 4];
            float4 h1 = *(const float4*)&sm.h.hs[1][kq * 256 + k4 * 4];
            float4 h2 = *(const float4*)&sm.h.hs[2][kq * 256 + k4 * 4];
            float4 h3 = *(const float4*)&sm.h.hs[3][kq * 256 + k4 * 4];
            a0 += w.x * h0.x + w.y * h0.y + w.z * h0.z + w.w * h0.w;
            a1 += w.x * h1.x + w.y * h1.y + w.z * h1.z + w.w * h1.w;
            a2 += w.x * h2.x + w.y * h2.y + w.z * h2.z + w.w * h2.w;
            a3 += w.x * h3.x + w.y * h3.y + w.z * h3.z + w.w * h3.w;
        }
        sm.h.pps[kq][0][gi2] = a0; sm.h.pps[kq][1][gi2] = a1;
        sm.h.pps[kq][2][gi2] = a2; sm.h.pps[kq][3][gi2] = a3;
    }
    __syncthreads();
    for (int idx = tid; idx < 400; idx += 256) {
        const int r = idx / 100, gi2 = idx % 100;
        float v = b1[gi2] + sm.h.pps[0][r][gi2] + sm.h.pps[1][r][gi2];
        sm.h.ps[r][gi2] = v > 0.f ? v : 0.f;
    }
    __syncthreads();

    // ---- phase 3: logits = p @ W2^T + b2; each thread: 4 vocab rows x all 4 batch rows
    const int v0 = tid * 4;
    float accv[4][4];  // [vi][r]
#pragma unroll
    for (int vi = 0; vi < 4; vi++) {
        const float bb = b2[v0 + vi];
#pragma unroll
        for (int r = 0; r < 4; r++) accv[vi][r] = bb;
    }
#pragma unroll 5
    for (int j4 = 0; j4 < 25; j4++) {
        float4 p0 = *(const float4*)&sm.h.ps[0][j4 * 4];
        float4 p1 = *(const float4*)&sm.h.ps[1][j4 * 4];
        float4 p2 = *(const float4*)&sm.h.ps[2][j4 * 4];
        float4 p3 = *(const float4*)&sm.h.ps[3][j4 * 4];
#pragma unroll
        for (int vi = 0; vi < 4; vi++) {
            float4 w = *(const float4*)&W2[(size_t)(v0 + vi) * GEN_ + j4 * 4];
            accv[vi][0] += w.x * p0.x + w.y * p0.y + w.z * p0.z + w.w * p0.w;
            accv[vi][1] += w.x * p1.x + w.y * p1.y + w.z * p1.z + w.w * p1.w;
            accv[vi][2] += w.x * p2.x + w.y * p2.y + w.z * p2.z + w.w * p2.w;
            accv[vi][3] += w.x * p3.x + w.y * p3.y + w.z * p3.z + w.w * p3.w;
        }
    }

    // ---- per-row max + argmax (first-index tie-break, matching np.argmax)
    float lmax[4]; int lidx[4];
#pragma unroll
    for (int r = 0; r < 4; r++) {
        lmax[r] = accv[0][r]; lidx[r] = v0;
#pragma unroll
        for (int vi = 1; vi < 4; vi++)
            if (accv[vi][r] > lmax[r]) { lmax[r] = accv[vi][r]; lidx[r] = v0 + vi; }
    }
#pragma unroll
    for (int off = 32; off; off >>= 1) {
#pragma unroll
        for (int r = 0; r < 4; r++) {
            float ov = __shfl_xor(lmax[r], off);
            int   oi = __shfl_xor(lidx[r], off);
            if (ov > lmax[r] || (ov == lmax[r] && oi < lidx[r])) { lmax[r] = ov; lidx[r] = oi; }
        }
    }
    const int wv = tid >> 6, lane = tid & 63;
    if (lane == 0) {
#pragma unroll
        for (int r = 0; r < 4; r++) { sm.h.red[r][wv] = lmax[r]; sm.h.redi[r][wv] = lidx[r]; }
    }
    __syncthreads();
    float rmax[4]; int ridx[4];
#pragma unroll
    for (int r = 0; r < 4; r++) {
        rmax[r] = sm.h.red[r][0]; ridx[r] = sm.h.redi[r][0];
#pragma unroll
        for (int w = 1; w < 4; w++)
            if (sm.h.red[r][w] > rmax[r] || (sm.h.red[r][w] == rmax[r] && sm.h.redi[r][w] < ridx[r])) {
                rmax[r] = sm.h.red[r][w]; ridx[r] = sm.h.redi[r][w];
            }
    }
    __syncthreads();  // before reusing red[]

    // ---- sum(exp(x - max))
    float ls[4];
#pragma unroll
    for (int r = 0; r < 4; r++)
        ls[r] = expf(accv[0][r] - rmax[r]) + expf(accv[1][r] - rmax[r]) +
                expf(accv[2][r] - rmax[r]) + expf(accv[3][r] - rmax[r]);
#pragma unroll
    for (int off = 32; off; off >>= 1) {
#pragma unroll
        for (int r = 0; r < 4; r++) ls[r] += __shfl_xor(ls[r], off);
    }
    if (lane == 0) {
#pragma unroll
        for (int r = 0; r < 4; r++) sm.h.red[r][wv] = ls[r];
    }
    __syncthreads();
#pragma unroll
    for (int r = 0; r < 4; r++) {
        const float logZ = rmax[r] + logf(sm.h.red[r][0] + sm.h.red[r][1] + sm.h.red[r][2] + sm.h.red[r][3]);
        float4 o;
        o.x = accv[0][r] - logZ; o.y = accv[1][r] - logZ;
        o.z = accv[2][r] - logZ; o.w = accv[3][r] - logZ;
        *(float4*)&outt[(size_t)(b0 + r) * V_ + v0] = o;
    }
    if (tid == 0) {
        tok[b0 + 0] = ridx[0]; tok[b0 + 1] = ridx[1];
        tok[b0 + 2] = ridx[2]; tok[b0 + 3] = ridx[3];
    }
}

// ---------------- host ----------------
extern "C" void kernel_launch(void* const* d_in, const int* in_sizes, int n_in,
                              void* d_out, int out_size, void* d_ws, size_t ws_size,
                              hipStream_t stream) {
    const float* input   = (const float*)d_in[0];
    const float* onehots = (const float*)d_in[1];
    // d_in[2] digits (unused), d_in[3] teacher (==0, free-running path hardcoded)
    const float* Wh  = (const float*)d_in[4];
    const float* bh  = (const float*)d_in[5];
    const float* Wc  = (const float*)d_in[6];
    const float* bc  = (const float*)d_in[7];
    const float* Wih = (const float*)d_in[8];
    const float* Whh = (const float*)d_in[9];
    const float* bih = (const float*)d_in[10];
    const float* bhh = (const float*)d_in[11];
    const float* W1  = (const float*)d_in[12];
    const float* b1  = (const float*)d_in[13];
    const float* W2  = (const float*)d_in[14];
    const float* b2  = (const float*)d_in[15];
    float* out = (float*)d_out;

    char* ws = (char*)d_ws;
    float* gbuf  = (float*)(ws + OFF_G);
    float* cbuf  = (float*)(ws + OFF_C);
    float* WihT  = (float*)(ws + OFF_WIHT);
    short* acat  = (short*)(ws + OFF_ACAT);
    short* bcat  = (short*)(ws + OFF_BCAT);
    float* bsum  = (float*)(ws + OFF_BSUM);
    int*   tok   = (int*)(ws + OFF_TOK);
    float* hbuf  = (float*)(ws + OFF_H);

    k_init<<<(B_ * H_) / 256, 256, 0, stream>>>(input, Wh, bh, Wc, bc, bih, bhh, cbuf, acat, bsum);
    k_tok0<<<(B_ * V_) / 256, 256, 0, stream>>>(onehots, tok);
    k_transpose<<<(V_ * FH) / 256, 256, 0, stream>>>(Wih, WihT);
    k_prep<<<(FH * H_) / 256, 256, 0, stream>>>(Whh, bcat);

    // pre-gates for t=0 (gates-only launch: ngates == grid)
    k_fused<<<128, 256, 0, stream>>>(128, acat, bcat, gbuf, hbuf, tok,
                                     W1, b1, W2, b2, out);

    for (int t = 0; t < T_; t++) {
        k_cell<<<B_ / 2, 256, 0, stream>>>(gbuf, cbuf, acat, WihT, bsum, tok, hbuf);
        const int ngates = (t < T_ - 1) ? 128 : 0;  // last step: out-only
        k_fused<<<ngates + 256, 256, 0, stream>>>(ngates, acat, bcat, gbuf, hbuf, tok,
                                                  W1, b1, W2, b2, out + (size_t)t * B_ * V_);
    }
}